// Round 14
// baseline (488.052 us; speedup 1.0000x reference)
//
#include <hip/hip_runtime.h>
#include <hip/hip_bf16.h>
#include <hip/hip_cooperative_groups.h>
#include <stdint.h>

#define D_MODEL 1024
#define S_LEN   4096
#define BATCH   4
#define HEADS   16
#define DEPTH   64
#define ROWS    (BATCH*S_LEN)   // 16384
#define EPS_K_F 1e-6f
#define EPS_LN_F 1e-6f

namespace cg = cooperative_groups;

typedef __attribute__((ext_vector_type(8))) short short8;
typedef __attribute__((ext_vector_type(4))) float f32x4;

__device__ __forceinline__ unsigned short f2bf(float f) {
  union { float f; unsigned u; } x; x.f = f;
  unsigned r = x.u + 0x7FFF + ((x.u >> 16) & 1);
  return (unsigned short)(r >> 16);
}
__device__ __forceinline__ float bf2f(unsigned short b) {
  union { unsigned u; float f; } x; x.u = ((unsigned)b) << 16;
  return x.f;
}
__device__ __forceinline__ void gload16(const void* g, void* l) {
  __builtin_amdgcn_global_load_lds(
      (const __attribute__((address_space(1))) void*)g,
      (__attribute__((address_space(3))) void*)l, 16, 0, 0);
}

// ---------------- f32 -> bf16 convert (q only; k,v ride GEMM sidecars) ------
__global__ __launch_bounds__(256) void cvt_f32_bf16_k(
    const float* __restrict__ in, unsigned short* __restrict__ out, int n4) {
  int i = blockIdx.x * 256 + threadIdx.x;
  if (i < n4) {
    float4 v = ((const float4*)in)[i];
    ushort4 o;
    o.x = f2bf(v.x); o.y = f2bf(v.y); o.z = f2bf(v.z); o.w = f2bf(v.w);
    ((ushort4*)out)[i] = o;
  }
}

// ---------------- weight transpose + convert: W[K,N] f32 -> Wt[N,K] bf16 ----
__global__ __launch_bounds__(256) void wtrans_k(
    const float* __restrict__ W, unsigned short* __restrict__ Wt) {
  __shared__ float tile[32][33];
  int n0 = blockIdx.x * 32, k0 = blockIdx.y * 32;
  int tx = threadIdx.x & 31, ty = threadIdx.x >> 5;
  #pragma unroll
  for (int i = 0; i < 32; i += 8)
    tile[ty + i][tx] = W[(size_t)(k0 + ty + i) * D_MODEL + n0 + tx];
  __syncthreads();
  #pragma unroll
  for (int i = 0; i < 32; i += 8)
    Wt[(size_t)(n0 + ty + i) * D_MODEL + k0 + tx] = f2bf(tile[tx][ty + i]);
}

// ===== fused GEMM+LN: 256x256 tile, 8 waves, BK=64, counted-vmcnt pipeline ==
// Main loop identical to R13 (swizzle slot = chunk ^ ((row>>1)&3), conflict-
// free; peeled tails; boundary vmcnt(8)/vmcnt(11)). Epilogue: bias (MODE 3)
// -> psum/psq partials -> grid.sync() (cooperative, 256 blocks = 1/CU) ->
// per-block stats pass into dead LDS -> LN applied to acc in regs -> write
// final activations (no Cb round-trip). MODE: 0 relu+eps; 1 (relu+eps)*mask;
// 2 ln*mask; 3 +bias, f32 out (final LN).
// Aliasing safety: ALL A reads complete before grid.sync; epilogue writes
// (possibly to the same buffer) happen after.

#define STAGE_HALF(kof_, slot_, h_) do {                                     \
    _Pragma("unroll")                                                        \
    for (int j = 0; j < 2; ++j) {                                            \
      int idx = j * 512 + t; int r_ = idx >> 2; int cs_ = idx & 3;           \
      int c_ = cs_ ^ ((r_ >> 1) & 3);                                        \
      gload16(A + (m0 + r_) * (size_t)D_MODEL + (kof_) + (h_) * 32 + c_ * 8, \
              &Al[slot_][(h_) * 8192 + idx * 8]);                            \
    }                                                                        \
    _Pragma("unroll")                                                        \
    for (int j = 0; j < 2; ++j) {                                            \
      int idx = j * 512 + t; int r_ = idx >> 2; int cs_ = idx & 3;           \
      int c_ = cs_ ^ ((r_ >> 1) & 3);                                        \
      gload16(Bt + (n0 + r_) * (size_t)D_MODEL + (kof_) + (h_) * 32 + c_ * 8,\
              &Bl[slot_][(h_) * 8192 + idx * 8]);                            \
    }                                                                        \
  } while (0)

#define PH_READ_B(kk_)                                                       \
    _Pragma("unroll")                                                        \
    for (int n = 0; n < 4; ++n) {                                            \
      int rb_ = wcn * 64 + n * 16 + l15;                                     \
      bfr[n] = *(const short8*)&Bl[slot][(kk_) * 8192 + rb_ * 32 + cswz];    \
    }
#define PH_READ_A(kk_, mh_)                                                  \
    _Pragma("unroll")                                                        \
    for (int m = 0; m < 4; ++m) {                                            \
      int ra_ = wr * 128 + ((mh_) * 4 + m) * 16 + l15;                       \
      af[m] = *(const short8*)&Al[slot][(kk_) * 8192 + ra_ * 32 + cswz];     \
    }
#define PH_MFMA(mh_)                                                         \
    __builtin_amdgcn_s_setprio(1);                                           \
    _Pragma("unroll")                                                        \
    for (int m = 0; m < 4; ++m)                                              \
      _Pragma("unroll")                                                      \
      for (int n = 0; n < 4; ++n)                                            \
        acc[(mh_) * 4 + m][n] = __builtin_amdgcn_mfma_f32_16x16x32_bf16(     \
            af[m], bfr[n], acc[(mh_) * 4 + m][n], 0, 0, 0);                  \
    __builtin_amdgcn_s_setprio(0);
#define LGKM0                                                                \
    asm volatile("s_waitcnt lgkmcnt(0)" ::: "memory");                       \
    __builtin_amdgcn_sched_barrier(0);

#define SIDE_PACK_STORE(chunk_) do {                                         \
    uint4 pk_;                                                               \
    pk_.x = (unsigned)f2bf(sreg0.x) | ((unsigned)f2bf(sreg0.y) << 16);       \
    pk_.y = (unsigned)f2bf(sreg0.z) | ((unsigned)f2bf(sreg0.w) << 16);       \
    pk_.z = (unsigned)f2bf(sreg1.x) | ((unsigned)f2bf(sreg1.y) << 16);       \
    pk_.w = (unsigned)f2bf(sreg1.z) | ((unsigned)f2bf(sreg1.w) << 16);       \
    *(uint4*)(side_dst + sbase + (size_t)(chunk_) * 4096) = pk_;             \
  } while (0)
#define SIDE_LOAD(chunk_) do {                                               \
    const float* sp_ = side_src + sbase + (size_t)(chunk_) * 4096;           \
    sreg0 = *(const float4*)sp_; sreg1 = *(const float4*)(sp_ + 4);          \
  } while (0)

#define TAIL_TILE(slot_) do {                                                \
    const int slot = (slot_);                                                \
    short8 af[4], bfr[4];                                                    \
    PH_READ_B(0) PH_READ_A(0, 0) LGKM0 PH_MFMA(0)                            \
    PH_READ_A(0, 1) LGKM0 PH_MFMA(1)                                         \
    PH_READ_B(1) PH_READ_A(1, 0) LGKM0 PH_MFMA(0)                            \
    PH_READ_A(1, 1) LGKM0 PH_MFMA(1)                                         \
  } while (0)

template <bool SIDECAR, int MODE>
__global__ __launch_bounds__(512) void gemm_fused_k(
    const unsigned short* __restrict__ A,
    const unsigned short* __restrict__ Bt,
    float* __restrict__ psum, float* __restrict__ psq,
    const float* __restrict__ bias,
    const float* __restrict__ side_src,
    unsigned short* __restrict__ side_dst,
    const float* __restrict__ gamma, const float* __restrict__ beta,
    const float* __restrict__ maskp,
    unsigned short* __restrict__ outb, float* __restrict__ outf) {
  __shared__ unsigned short Al[2][16384];
  __shared__ unsigned short Bl[2][16384];
  int t = threadIdx.x;
  int lane = t & 63, wid = t >> 6;
  int wr = wid >> 2, wcn = wid & 3;
  int l15 = lane & 15, lhi = lane >> 4;
  const int cswz = (lhi ^ ((l15 >> 1) & 3)) << 3;  // conflict-free swizzle
  int p = blockIdx.x;
  int cb = (p >> 3) & 3;
  int rb = (p & 7) | ((p >> 5) << 3);
  size_t m0 = (size_t)rb * 256, n0 = (size_t)cb * 256;
  f32x4 acc[8][4] = {};

  const int KT = D_MODEL >> 6;            // 16 K-tiles of 64

  float4 sreg0 = {}, sreg1 = {};
  size_t sbase = (size_t)p * 65536 + (size_t)t * 8;

  if (SIDECAR) SIDE_LOAD(0);
  STAGE_HALF(0, 0, 0);  STAGE_HALF(0, 0, 1);
  STAGE_HALF(64, 1, 0); STAGE_HALF(64, 1, 1);
  asm volatile("s_waitcnt vmcnt(8)" ::: "memory");
  __builtin_amdgcn_s_barrier();
  __builtin_amdgcn_sched_barrier(0);

  for (int kt = 0; kt < KT - 2; ++kt) {
    const int slot = kt & 1;
    short8 af[4], bfr[4];
    PH_READ_B(0)
    PH_READ_A(0, 0)
    LGKM0
    PH_MFMA(0)
    PH_READ_A(0, 1)
    LGKM0
    __builtin_amdgcn_s_barrier();
    __builtin_amdgcn_sched_barrier(0);
    STAGE_HALF((kt + 2) << 6, slot, 0);
    __builtin_amdgcn_sched_barrier(0);
    PH_MFMA(1)
    PH_READ_B(1)
    PH_READ_A(1, 0)
    LGKM0
    PH_MFMA(0)
    PH_READ_A(1, 1)
    LGKM0
    __builtin_amdgcn_s_barrier();
    __builtin_amdgcn_sched_barrier(0);
    STAGE_HALF((kt + 2) << 6, slot, 1);
    __builtin_amdgcn_sched_barrier(0);
    PH_MFMA(1)
    if (SIDECAR) {
      SIDE_PACK_STORE(kt);
      SIDE_LOAD(kt + 1);
      __builtin_amdgcn_sched_barrier(0);
      asm volatile("s_waitcnt vmcnt(11)" ::: "memory");
    } else {
      asm volatile("s_waitcnt vmcnt(8)" ::: "memory");
    }
    __builtin_amdgcn_s_barrier();
    __builtin_amdgcn_sched_barrier(0);
  }

  TAIL_TILE((KT - 2) & 1);
  if (SIDECAR) {
    SIDE_PACK_STORE(KT - 2);
    SIDE_LOAD(KT - 1);
    __builtin_amdgcn_sched_barrier(0);
    asm volatile("s_waitcnt vmcnt(3)" ::: "memory");
  } else {
    asm volatile("s_waitcnt vmcnt(0)" ::: "memory");
  }
  __builtin_amdgcn_s_barrier();
  __builtin_amdgcn_sched_barrier(0);

  TAIL_TILE((KT - 1) & 1);
  if (SIDECAR) SIDE_PACK_STORE(KT - 1);

  // ---- epilogue part 1: bias (final-LN mode; stats must include it) ----
  if (MODE == 3) {
    float bv[4];
    #pragma unroll
    for (int n = 0; n < 4; ++n)
      bv[n] = bias[(int)n0 + wcn * 64 + n * 16 + l15];
    #pragma unroll
    for (int m = 0; m < 8; ++m)
      #pragma unroll
      for (int n = 0; n < 4; ++n)
        #pragma unroll
        for (int j = 0; j < 4; ++j)
          acc[m][n][j] += bv[n];
  }

  // ---- epilogue part 2: per-row partial sum/sumsq over this wave's 64 cols
  {
    int seg = (int)(n0 >> 6) + wcn;
    #pragma unroll
    for (int m = 0; m < 8; ++m) {
      float s[4], s2[4];
      #pragma unroll
      for (int j = 0; j < 4; ++j) {
        float a = 0.f, b = 0.f;
        #pragma unroll
        for (int n = 0; n < 4; ++n) { float x = acc[m][n][j]; a += x; b += x * x; }
        s[j] = a; s2[j] = b;
      }
      #pragma unroll
      for (int off = 1; off < 16; off <<= 1) {
        #pragma unroll
        for (int j = 0; j < 4; ++j) {
          s[j]  += __shfl_xor(s[j],  off);
          s2[j] += __shfl_xor(s2[j], off);
        }
      }
      if (l15 == 0) {
        #pragma unroll
        for (int j = 0; j < 4; ++j) {
          int rg = (int)m0 + wr * 128 + m * 16 + lhi * 4 + j;
          psum[rg * 16 + seg] = s[j];
          psq [rg * 16 + seg] = s2[j];
        }
      }
    }
  }

  // ---- grid-wide sync: all partials visible, all A reads complete ----
  cg::this_grid().sync();

  // ---- epilogue part 3: stats pass into (dead) LDS ----
  float* meanl = (float*)&Al[0][0];
  float* rstdl = meanl + 256;
  float* maskl = rstdl + 256;
  for (int r = t; r < 256; r += 512) {
    int row = (int)m0 + r;
    float s = 0.f, s2 = 0.f;
    #pragma unroll
    for (int i = 0; i < 16; ++i) { s += psum[row * 16 + i]; s2 += psq[row * 16 + i]; }
    float mean = s * (1.f / D_MODEL);
    float var = s2 * (1.f / D_MODEL) - mean * mean;
    meanl[r] = mean;
    rstdl[r] = rsqrtf(var + EPS_LN_F);
    if (MODE == 1 || MODE == 2) maskl[r] = maskp[row];
  }
  __syncthreads();

  // ---- epilogue part 4: LN + activation applied to acc, final write ----
  float gv[4], bv2[4];
  #pragma unroll
  for (int n = 0; n < 4; ++n) {
    int col = (int)n0 + wcn * 64 + n * 16 + l15;
    gv[n] = gamma[col]; bv2[n] = beta[col];
  }
  #pragma unroll
  for (int m = 0; m < 8; ++m)
    #pragma unroll
    for (int j = 0; j < 4; ++j) {
      int rl = wr * 128 + m * 16 + lhi * 4 + j;
      size_t row = m0 + rl;
      float mean = meanl[rl], rstd = rstdl[rl];
      float mk = (MODE == 1 || MODE == 2) ? maskl[rl] : 1.f;
      #pragma unroll
      for (int n = 0; n < 4; ++n) {
        int col = (int)n0 + wcn * 64 + n * 16 + l15;
        float ln = (acc[m][n][j] - mean) * rstd * gv[n] + bv2[n];
        if (MODE == 0)      ln = fmaxf(ln, 0.f) + EPS_K_F;
        else if (MODE == 1) ln = (fmaxf(ln, 0.f) + EPS_K_F) * mk;
        else if (MODE == 2) ln = ln * mk;
        if (MODE == 3) outf[row * D_MODEL + col] = ln;
        else           outb[row * D_MODEL + col] = f2bf(ln);
      }
    }
}

// ---------------- KV via MFMA with swizzled-LDS transpose -------------------
__global__ __launch_bounds__(256) void kv_mfma_k(
    const unsigned short* __restrict__ Kp, const unsigned short* __restrict__ Vp,
    float* __restrict__ part, float* __restrict__ kspart) {
  __shared__ unsigned short Kl[4096];
  __shared__ unsigned short Vl[4096];
  int bh = blockIdx.y, chunk = blockIdx.x;   // chunk 0..7, 512 n each
  int b_ = bh >> 4, h = bh & 15;
  int t = threadIdx.x, lane = t & 63, w = t >> 6;
  int l15 = lane & 15, g = lane >> 4;        // g in 0..3

  int sn = t >> 2, sd16 = t & 3;
  int sc = sd16 ^ ((sn >> 3) & 3);
  size_t goff = (size_t)sn * D_MODEL + h * DEPTH + sd16 * 16;
  int ldst = sn * 64 + sc * 16;

  short8 ones;
  #pragma unroll
  for (int i = 0; i < 8; ++i) ones[i] = (short)0x3F80;

  f32x4 acc[4] = {};
  f32x4 ks = {};

  int baseA = ((w ^ g) << 4) + l15;
  int baseB0 = ((0 ^ g) << 4) + l15;
  int baseB1 = ((1 ^ g) << 4) + l15;
  int baseB2 = ((2 ^ g) << 4) + l15;
  int baseB3 = ((3 ^ g) << 4) + l15;

  size_t rowbase = ((size_t)b_ * S_LEN + (size_t)chunk * 512) * D_MODEL;
  for (int tile = 0; tile < 8; ++tile) {
    const unsigned short* kg = Kp + rowbase + (size_t)tile * 64 * D_MODEL + goff;
    const unsigned short* vg = Vp + rowbase + (size_t)tile * 64 * D_MODEL + goff;
    uint4 ra = *(const uint4*)kg;
    uint4 rb = *(const uint4*)(kg + 8);
    uint4 rc = *(const uint4*)vg;
    uint4 rd = *(const uint4*)(vg + 8);
    __syncthreads();
    *(uint4*)&Kl[ldst]     = ra;
    *(uint4*)&Kl[ldst + 8] = rb;
    *(uint4*)&Vl[ldst]     = rc;
    *(uint4*)&Vl[ldst + 8] = rd;
    __syncthreads();
    #pragma unroll
    for (int kk = 0; kk < 2; ++kk) {
      int nb = (kk * 32 + g * 8) * 64;
      short8 af, bf0, bf1, bf2, bf3;
      #pragma unroll
      for (int i = 0; i < 8; ++i) {
        int rowoff = nb + i * 64;
        af[i]  = (short)Kl[rowoff + baseA];
        bf0[i] = (short)Vl[rowoff + baseB0];
        bf1[i] = (short)Vl[rowoff + baseB1];
        bf2[i] = (short)Vl[rowoff + baseB2];
        bf3[i] = (short)Vl[rowoff + baseB3];
      }
      acc[0] = __builtin_amdgcn_mfma_f32_16x16x32_bf16(af, bf0, acc[0], 0, 0, 0);
      acc[1] = __builtin_amdgcn_mfma_f32_16x16x32_bf16(af, bf1, acc[1], 0, 0, 0);
      acc[2] = __builtin_amdgcn_mfma_f32_16x16x32_bf16(af, bf2, acc[2], 0, 0, 0);
      acc[3] = __builtin_amdgcn_mfma_f32_16x16x32_bf16(af, bf3, acc[3], 0, 0, 0);
      ks     = __builtin_amdgcn_mfma_f32_16x16x32_bf16(af, ones, ks, 0, 0, 0);
    }
  }
  float* pp = part + ((size_t)bh * 8 + chunk) * 4096;
  #pragma unroll
  for (int nf = 0; nf < 4; ++nf)
    #pragma unroll
    for (int r = 0; r < 4; ++r)
      pp[(16 * w + 4 * g + r) * 64 + 16 * nf + l15] = acc[nf][r];
  if (l15 == 0) {
    #pragma unroll
    for (int r = 0; r < 4; ++r)
      kspart[((size_t)bh * 8 + chunk) * 64 + 16 * w + 4 * g + r] = ks[r];
  }
}

// ---------------- KV reduce -> KV^T bf16 ([e][d]) + ksum f32 ----------------
__global__ __launch_bounds__(256) void kv_reduce_k(
    const float* __restrict__ part, const float* __restrict__ kspart,
    unsigned short* __restrict__ KVT, float* __restrict__ ksum) {
  int bh = blockIdx.x, t = threadIdx.x;
  for (int idx = t; idx < 4096; idx += 256) {
    int d = idx >> 6, e = idx & 63;
    float s = 0.f;
    #pragma unroll
    for (int c = 0; c < 8; ++c)
      s += part[((size_t)bh * 8 + c) * 4096 + d * 64 + e];
    KVT[(size_t)bh * 4096 + e * 64 + d] = f2bf(s);
  }
  if (t < 64) {
    float s = 0.f;
    #pragma unroll
    for (int c = 0; c < 8; ++c) s += kspart[((size_t)bh * 8 + c) * 64 + t];
    ksum[bh * 64 + t] = s;
  }
}

// ---------------- att = (q' @ KV) * z, written in the reference's reshape ---
__global__ __launch_bounds__(256) void att_k(
    const unsigned short* __restrict__ Qp, const unsigned short* __restrict__ KVT,
    const float* __restrict__ ksum, unsigned short* __restrict__ att) {
  __shared__ unsigned short Ql[128 * 64];
  __shared__ unsigned short Kl[64 * 64];
  __shared__ float ksl[64];
  __shared__ float zl[128];
  int bh = blockIdx.y;
  int b = bh >> 4, h = bh & 15;
  int r0 = blockIdx.x * 128;
  int t = threadIdx.x, lane = t & 63, wid = t >> 6;
  int l15 = lane & 15, lhi = lane >> 4;
  #pragma unroll
  for (int i = 0; i < 4; ++i) {
    int cid = i * 256 + t;
    int r = cid >> 3, c8 = cid & 7;
    gload16(Qp + ((size_t)(b * S_LEN + r0 + r)) * D_MODEL + h * DEPTH + c8 * 8,
            &Ql[cid * 8]);
  }
  #pragma unroll
  for (int i = 0; i < 2; ++i) {
    int cid = i * 256 + t;
    gload16(KVT + (size_t)bh * 4096 + cid * 8, &Kl[cid * 8]);
  }
  if (t < 64) ksl[t] = ksum[bh * 64 + t];
  asm volatile("s_waitcnt vmcnt(0)" ::: "memory");
  __syncthreads();
  {
    int r = t >> 1, half = t & 1;
    float s = 0.f;
    #pragma unroll
    for (int j = 0; j < 32; ++j)
      s += bf2f(Ql[r * 64 + half * 32 + j]) * ksl[half * 32 + j];
    s += __shfl_xor(s, 1);
    if (half == 0) zl[r] = 1.f / (s + EPS_K_F);
  }
  __syncthreads();
  f32x4 acc[2][4] = {};
  #pragma unroll
  for (int kk = 0; kk < 2; ++kk) {
    short8 af[2], bfr[4];
    #pragma unroll
    for (int m = 0; m < 2; ++m)
      af[m] = *(const short8*)&Ql[(wid * 32 + m * 16 + l15) * 64 + kk * 32 + lhi * 8];
    #pragma unroll
    for (int n = 0; n < 4; ++n)
      bfr[n] = *(const short8*)&Kl[(n * 16 + l15) * 64 + kk * 32 + lhi * 8];
    #pragma unroll
    for (int m = 0; m < 2; ++m)
      #pragma unroll
      for (int n = 0; n < 4; ++n)
        acc[m][n] = __builtin_amdgcn_mfma_f32_16x16x32_bf16(af[m], bfr[n], acc[m][n], 0, 0, 0);
  }
  #pragma unroll
  for (int m = 0; m < 2; ++m)
    #pragma unroll
    for (int j = 0; j < 4; ++j) {
      int rl = wid * 32 + m * 16 + lhi * 4 + j;
      int n = r0 + rl;
      float z = zl[rl];
      #pragma unroll
      for (int nf = 0; nf < 4; ++nf) {
        int ee = nf * 16 + l15;
        size_t orow = (size_t)b * S_LEN + h * 256 + (n >> 4);
        int ocol = (n & 15) * 64 + ee;
        att[orow * D_MODEL + ocol] = f2bf(acc[m][nf][j] * z);
      }
    }
}

extern "C" void kernel_launch(void* const* d_in, const int* in_sizes, int n_in,
                              void* d_out, int out_size, void* d_ws, size_t ws_size,
                              hipStream_t stream) {
  (void)in_sizes; (void)n_in; (void)out_size; (void)ws_size;
  const float* q     = (const float*)d_in[0];
  const float* k     = (const float*)d_in[1];
  const float* v     = (const float*)d_in[2];
  const float* mask  = (const float*)d_in[3];
  const float* wq    = (const float*)d_in[4];
  const float* wk    = (const float*)d_in[5];
  const float* wv    = (const float*)d_in[6];
  const float* gamma = (const float*)d_in[7];
  const float* beta  = (const float*)d_in[8];
  const float* dw    = (const float*)d_in[9];
  const float* db    = (const float*)d_in[10];
  float* out = (float*)d_out;

  char* ws = (char*)d_ws;
  // buffer plan (lifetimes hand-verified):
  //   ws+0   : Xq (cvt) -> read by gemm_q (all reads pre-sync) -> Qp written
  //            by gemm_q epilogue (post-sync) -> read by att.
  //   ws+32M : Xk (gemm_q sidecar) -> gemm_k A -> Kp (epilogue) -> kv_mfma.
  //   ws+64M : Xv (gemm_k sidecar) -> gemm_v A -> Vp (epilogue) -> kv_mfma.
  //   ws+96M : weights; ws+104M: part; ws+112M: kspart/KVT/ksum; psum/psq.
  //   d_out  : att output (bf16, first 32 MB) -> gemm_d A (reads pre-sync)
  //            -> f32 final out written post-sync.
  unsigned short* Xq  = (unsigned short*)(ws);
  unsigned short* Xk  = (unsigned short*)(ws + 33554432);
  unsigned short* Xv  = (unsigned short*)(ws + 67108864);
  unsigned short* Qp  = Xq;
  unsigned short* Kp  = Xk;
  unsigned short* Vp  = Xv;
  unsigned short* WqT = (unsigned short*)(ws + 100663296);
  unsigned short* WkT = WqT + 1048576;
  unsigned short* WvT = WkT + 1048576;
  unsigned short* WdT = WvT + 1048576;
  float* part   = (float*)(ws + 109051904);
  float* kspart = (float*)(ws + 117440512);
  unsigned short* KVT = (unsigned short*)(ws + 117964800);
  float* ksum = (float*)(ws + 118489088);
  float* psum = (float*)(ws + 119537664);   // 1 MB
  float* psq  = (float*)(ws + 120586240);   // 1 MB
  unsigned short* Cqkv = (unsigned short*)d_out;   // att out / gemm_d A

  const float* nob = nullptr;
  const float* nosrc = nullptr;
  unsigned short* nodst = nullptr;
  unsigned short* noub = nullptr;
  float* nouf = nullptr;

  dim3 b256(256);
  dim3 b512(512);
  int n4 = ROWS * D_MODEL / 4;
  dim3 cvtg(n4 / 256);
  dim3 wtg(32, 32);
  dim3 gemmg(256);            // (M/256)*(N/256), XCD-swizzled in-kernel
  
  wtrans_k<<<wtg, b256, 0, stream>>>(wq, WqT);
  wtrans_k<<<wtg, b256, 0, stream>>>(wk, WkT);
  wtrans_k<<<wtg, b256, 0, stream>>>(wv, WvT);
  wtrans_k<<<wtg, b256, 0, stream>>>(dw, WdT);

  cvt_f32_bf16_k<<<cvtg, b256, 0, stream>>>(q, Xq, n4);

  // gemm_q + LN(relu,+eps) -> Qp ; sidecar converts k -> Xk
  {
    void* a[] = {(void*)&Xq, (void*)&WqT, (void*)&psum, (void*)&psq, (void*)&nob,
                 (void*)&k, (void*)&Xk, (void*)&gamma, (void*)&beta, (void*)&mask,
                 (void*)&Qp, (void*)&nouf};
    hipLaunchCooperativeKernel((void*)gemm_fused_k<true, 0>, gemmg, b512, a, 0, stream);
  }
  // gemm_k + LN(relu,+eps,*mask) -> Kp ; sidecar converts v -> Xv
  {
    void* a[] = {(void*)&Xk, (void*)&WkT, (void*)&psum, (void*)&psq, (void*)&nob,
                 (void*)&v, (void*)&Xv, (void*)&gamma, (void*)&beta, (void*)&mask,
                 (void*)&Kp, (void*)&nouf};
    hipLaunchCooperativeKernel((void*)gemm_fused_k<true, 1>, gemmg, b512, a, 0, stream);
  }
  // gemm_v + LN(*mask) -> Vp
  {
    void* a[] = {(void*)&Xv, (void*)&WvT, (void*)&psum, (void*)&psq, (void*)&nob,
                 (void*)&nosrc, (void*)&nodst, (void*)&gamma, (void*)&beta, (void*)&mask,
                 (void*)&Vp, (void*)&nouf};
    hipLaunchCooperativeKernel((void*)gemm_fused_k<false, 2>, gemmg, b512, a, 0, stream);
  }

  kv_mfma_k<<<dim3(8, 64), b256, 0, stream>>>(Kp, Vp, part, kspart);
  kv_reduce_k<<<dim3(64), b256, 0, stream>>>(part, kspart, KVT, ksum);
  att_k<<<dim3(32, 64), b256, 0, stream>>>(Qp, KVT, ksum, Cqkv);

  // gemm_d + bias + final LN -> f32 out
  {
    void* a[] = {(void*)&Cqkv, (void*)&WdT, (void*)&psum, (void*)&psq, (void*)&db,
                 (void*)&nosrc, (void*)&nodst, (void*)&gamma, (void*)&beta, (void*)&mask,
                 (void*)&noub, (void*)&out};
    hipLaunchCooperativeKernel((void*)gemm_fused_k<false, 3>, gemmg, b512, a, 0, stream);
  }
}

// Round 15
// 335.918 us; speedup vs baseline: 1.4529x; 1.4529x over previous
//
#include <hip/hip_runtime.h>
#include <hip/hip_bf16.h>
#include <stdint.h>

#define D_MODEL 1024
#define S_LEN   4096
#define BATCH   4
#define HEADS   16
#define DEPTH   64
#define ROWS    (BATCH*S_LEN)   // 16384
#define EPS_K_F 1e-6f
#define EPS_LN_F 1e-6f

typedef __attribute__((ext_vector_type(8))) short short8;
typedef __attribute__((ext_vector_type(4))) float f32x4;

__device__ __forceinline__ unsigned short f2bf(float f) {
  union { float f; unsigned u; } x; x.f = f;
  unsigned r = x.u + 0x7FFF + ((x.u >> 16) & 1);
  return (unsigned short)(r >> 16);
}
__device__ __forceinline__ float bf2f(unsigned short b) {
  union { unsigned u; float f; } x; x.u = ((unsigned)b) << 16;
  return x.f;
}
__device__ __forceinline__ void gload16(const void* g, void* l) {
  __builtin_amdgcn_global_load_lds(
      (const __attribute__((address_space(1))) void*)g,
      (__attribute__((address_space(3))) void*)l, 16, 0, 0);
}

// -------- weight transpose + convert, with q-conversion sidecar -------------
// Transpose W[K,N] f32 -> Wt[N,K] bf16. Sidecar: convert slice of q
// (4,194,304 f32) to bf16: 1024 blocks x 4096 elems (2 iters x 8/thread).
__global__ __launch_bounds__(256) void wtrans_k(
    const float* __restrict__ W, unsigned short* __restrict__ Wt,
    const float* __restrict__ qsrc, unsigned short* __restrict__ qdst,
    int slice) {
  __shared__ float tile[32][33];
  int n0 = blockIdx.x * 32, k0 = blockIdx.y * 32;
  int tx = threadIdx.x & 31, ty = threadIdx.x >> 5;
  #pragma unroll
  for (int i = 0; i < 32; i += 8)
    tile[ty + i][tx] = W[(size_t)(k0 + ty + i) * D_MODEL + n0 + tx];
  // q-convert sidecar (independent of the transpose; overlaps its latency)
  if (qsrc) {
    int bid = blockIdx.y * 32 + blockIdx.x;
    size_t base = (size_t)slice * 4194304 + (size_t)bid * 4096 +
                  (size_t)threadIdx.x * 8;
    #pragma unroll
    for (int it = 0; it < 2; ++it) {
      size_t off = base + (size_t)it * 2048;
      float4 a = *(const float4*)(qsrc + off);
      float4 b = *(const float4*)(qsrc + off + 4);
      uint4 pk;
      pk.x = (unsigned)f2bf(a.x) | ((unsigned)f2bf(a.y) << 16);
      pk.y = (unsigned)f2bf(a.z) | ((unsigned)f2bf(a.w) << 16);
      pk.z = (unsigned)f2bf(b.x) | ((unsigned)f2bf(b.y) << 16);
      pk.w = (unsigned)f2bf(b.z) | ((unsigned)f2bf(b.w) << 16);
      *(uint4*)(qdst + off) = pk;
    }
  }
  __syncthreads();
  #pragma unroll
  for (int i = 0; i < 32; i += 8)
    Wt[(size_t)(n0 + ty + i) * D_MODEL + k0 + tx] = f2bf(tile[tx][ty + i]);
}

// ===== GEMM: 256x256 tile, 8 waves, BK=64, counted-vmcnt 4-phase pipeline ===
// LDS per tensor: [2 slots][2 kk-halves][256 rows x 32 k] bf16 (128 KB).
// Swizzle (involution, conflict-free): LDS slot s of row r holds global
// chunk s ^ ((r>>1)&3). Main loop peeled (staging unconditional); counted
// waits: boundary vmcnt(8) [sidecar: vmcnt(11)] keeps next tile in flight.

#define GEMM_EPILOGUE(HASBIAS)                                               \
  if (HASBIAS) {                                                             \
    float bv[4];                                                             \
    _Pragma("unroll")                                                        \
    for (int n = 0; n < 4; ++n)                                              \
      bv[n] = bias[(int)n0 + wcn * 64 + n * 16 + l15];                       \
    _Pragma("unroll")                                                        \
    for (int m = 0; m < 8; ++m)                                              \
      _Pragma("unroll")                                                      \
      for (int n = 0; n < 4; ++n)                                            \
        _Pragma("unroll")                                                    \
        for (int j = 0; j < 4; ++j)                                          \
          acc[m][n][j] += bv[n];                                             \
  }                                                                          \
  int seg = (int)(n0 >> 6) + wcn;                                            \
  _Pragma("unroll")                                                          \
  for (int m = 0; m < 8; ++m) {                                              \
    float s[4], s2[4];                                                       \
    _Pragma("unroll")                                                        \
    for (int j = 0; j < 4; ++j) {                                            \
      float a = 0.f, b = 0.f;                                                \
      _Pragma("unroll")                                                      \
      for (int n = 0; n < 4; ++n) { float x = acc[m][n][j]; a += x; b += x*x; } \
      s[j] = a; s2[j] = b;                                                   \
    }                                                                        \
    _Pragma("unroll")                                                        \
    for (int off = 1; off < 16; off <<= 1) {                                 \
      _Pragma("unroll")                                                      \
      for (int j = 0; j < 4; ++j) {                                          \
        s[j]  += __shfl_xor(s[j],  off);                                     \
        s2[j] += __shfl_xor(s2[j], off);                                     \
      }                                                                      \
    }                                                                        \
    if (l15 == 0) {                                                          \
      _Pragma("unroll")                                                      \
      for (int j = 0; j < 4; ++j) {                                          \
        int rg = (int)m0 + wr * 128 + m * 16 + lhi * 4 + j;                  \
        psum[rg * 16 + seg] = s[j];                                          \
        psq [rg * 16 + seg] = s2[j];                                         \
      }                                                                      \
    }                                                                        \
  }                                                                          \
  _Pragma("unroll")                                                          \
  for (int m = 0; m < 8; ++m)                                                \
    _Pragma("unroll")                                                        \
    for (int j = 0; j < 4; ++j) {                                            \
      size_t row = m0 + wr * 128 + m * 16 + lhi * 4 + j;                     \
      _Pragma("unroll")                                                      \
      for (int n = 0; n < 4; ++n) {                                          \
        int col = (int)n0 + wcn * 64 + n * 16 + l15;                         \
        Cb[row * N + col] = f2bf(acc[m][n][j]);                              \
      }                                                                      \
    }

#define STAGE_HALF(kof_, slot_, h_) do {                                     \
    _Pragma("unroll")                                                        \
    for (int j = 0; j < 2; ++j) {                                            \
      int idx = j * 512 + t; int r_ = idx >> 2; int cs_ = idx & 3;           \
      int c_ = cs_ ^ ((r_ >> 1) & 3);                                        \
      gload16(A + (m0 + r_) * (size_t)K + (kof_) + (h_) * 32 + c_ * 8,       \
              &Al[slot_][(h_) * 8192 + idx * 8]);                            \
    }                                                                        \
    _Pragma("unroll")                                                        \
    for (int j = 0; j < 2; ++j) {                                            \
      int idx = j * 512 + t; int r_ = idx >> 2; int cs_ = idx & 3;           \
      int c_ = cs_ ^ ((r_ >> 1) & 3);                                        \
      gload16(Bt + (n0 + r_) * (size_t)K + (kof_) + (h_) * 32 + c_ * 8,      \
              &Bl[slot_][(h_) * 8192 + idx * 8]);                            \
    }                                                                        \
  } while (0)

#define PH_READ_B(kk_)                                                       \
    _Pragma("unroll")                                                        \
    for (int n = 0; n < 4; ++n) {                                            \
      int rb_ = wcn * 64 + n * 16 + l15;                                     \
      bfr[n] = *(const short8*)&Bl[slot][(kk_) * 8192 + rb_ * 32 + cswz];    \
    }
#define PH_READ_A(kk_, mh_)                                                  \
    _Pragma("unroll")                                                        \
    for (int m = 0; m < 4; ++m) {                                            \
      int ra_ = wr * 128 + ((mh_) * 4 + m) * 16 + l15;                       \
      af[m] = *(const short8*)&Al[slot][(kk_) * 8192 + ra_ * 32 + cswz];     \
    }
#define PH_MFMA(mh_)                                                         \
    __builtin_amdgcn_s_setprio(1);                                           \
    _Pragma("unroll")                                                        \
    for (int m = 0; m < 4; ++m)                                              \
      _Pragma("unroll")                                                      \
      for (int n = 0; n < 4; ++n)                                            \
        acc[(mh_) * 4 + m][n] = __builtin_amdgcn_mfma_f32_16x16x32_bf16(     \
            af[m], bfr[n], acc[(mh_) * 4 + m][n], 0, 0, 0);                  \
    __builtin_amdgcn_s_setprio(0);
#define LGKM0                                                                \
    asm volatile("s_waitcnt lgkmcnt(0)" ::: "memory");                       \
    __builtin_amdgcn_sched_barrier(0);

#define SIDE_PACK_STORE(chunk_) do {                                         \
    uint4 pk_;                                                               \
    pk_.x = (unsigned)f2bf(sreg0.x) | ((unsigned)f2bf(sreg0.y) << 16);       \
    pk_.y = (unsigned)f2bf(sreg0.z) | ((unsigned)f2bf(sreg0.w) << 16);       \
    pk_.z = (unsigned)f2bf(sreg1.x) | ((unsigned)f2bf(sreg1.y) << 16);       \
    pk_.w = (unsigned)f2bf(sreg1.z) | ((unsigned)f2bf(sreg1.w) << 16);       \
    *(uint4*)(side_dst + sbase + (size_t)(chunk_) * 4096) = pk_;             \
  } while (0)
#define SIDE_LOAD(chunk_) do {                                               \
    const float* sp_ = side_src + sbase + (size_t)(chunk_) * 4096;           \
    sreg0 = *(const float4*)sp_; sreg1 = *(const float4*)(sp_ + 4);          \
  } while (0)

#define TAIL_TILE(slot_) do {                                                \
    const int slot = (slot_);                                                \
    short8 af[4], bfr[4];                                                    \
    PH_READ_B(0) PH_READ_A(0, 0) LGKM0 PH_MFMA(0)                            \
    PH_READ_A(0, 1) LGKM0 PH_MFMA(1)                                         \
    PH_READ_B(1) PH_READ_A(1, 0) LGKM0 PH_MFMA(0)                            \
    PH_READ_A(1, 1) LGKM0 PH_MFMA(1)                                         \
  } while (0)

template <bool SIDECAR>
__global__ __launch_bounds__(512) void gemm_bt_k(
    const unsigned short* __restrict__ A,
    const unsigned short* __restrict__ Bt,
    unsigned short* __restrict__ Cb,
    float* __restrict__ psum, float* __restrict__ psq,
    const float* __restrict__ bias,
    const float* __restrict__ side_src,      // f32 tensor to convert
    unsigned short* __restrict__ side_dst,   // bf16 destination
    int M, int N, int K) {
  __shared__ unsigned short Al[2][16384];
  __shared__ unsigned short Bl[2][16384];
  int t = threadIdx.x;
  int lane = t & 63, wid = t >> 6;
  int wr = wid >> 2, wcn = wid & 3;
  int l15 = lane & 15, lhi = lane >> 4;
  const int cswz = (lhi ^ ((l15 >> 1) & 3)) << 3;  // conflict-free swizzle
  int p = blockIdx.x;
  int cb = (p >> 3) & 3;
  int rb = (p & 7) | ((p >> 5) << 3);
  size_t m0 = (size_t)rb * 256, n0 = (size_t)cb * 256;
  f32x4 acc[8][4] = {};

  const int KT = K >> 6;                  // 16 K-tiles of 64 (K==1024)

  // sidecar: block p converts elems [p*65536,(p+1)*65536), 16 chunks of 4096
  float4 sreg0 = {}, sreg1 = {};
  size_t sbase = (size_t)p * 65536 + (size_t)t * 8;

  // prologue: chunk-0 load FIRST, then stage tiles 0,1; vmcnt(8) drains
  // chunk-0 loads + tile-0 staging, keeps tile-1 staging (8) in flight.
  if (SIDECAR) SIDE_LOAD(0);
  STAGE_HALF(0, 0, 0);  STAGE_HALF(0, 0, 1);
  STAGE_HALF(64, 1, 0); STAGE_HALF(64, 1, 1);
  asm volatile("s_waitcnt vmcnt(8)" ::: "memory");
  __builtin_amdgcn_s_barrier();
  __builtin_amdgcn_sched_barrier(0);

  for (int kt = 0; kt < KT - 2; ++kt) {
    const int slot = kt & 1;
    short8 af[4], bfr[4];
    // phase 1: kk0, mh0
    PH_READ_B(0)
    PH_READ_A(0, 0)
    LGKM0
    PH_MFMA(0)
    // phase 2: kk0, mh1 (+ stage half0 of tile kt+2 into this slot)
    PH_READ_A(0, 1)
    LGKM0
    __builtin_amdgcn_s_barrier();          // all waves done with kk0 reads
    __builtin_amdgcn_sched_barrier(0);
    STAGE_HALF((kt + 2) << 6, slot, 0);
    __builtin_amdgcn_sched_barrier(0);
    PH_MFMA(1)
    // phase 3: kk1, mh0
    PH_READ_B(1)
    PH_READ_A(1, 0)
    LGKM0
    PH_MFMA(0)
    // phase 4: kk1, mh1 (+ stage half1 of tile kt+2)
    PH_READ_A(1, 1)
    LGKM0
    __builtin_amdgcn_s_barrier();          // all waves done with kk1 reads
    __builtin_amdgcn_sched_barrier(0);
    STAGE_HALF((kt + 2) << 6, slot, 1);
    __builtin_amdgcn_sched_barrier(0);
    PH_MFMA(1)
    // boundary
    if (SIDECAR) {
      SIDE_PACK_STORE(kt);
      SIDE_LOAD(kt + 1);
      __builtin_amdgcn_sched_barrier(0);
      asm volatile("s_waitcnt vmcnt(11)" ::: "memory");
    } else {
      asm volatile("s_waitcnt vmcnt(8)" ::: "memory");
    }
    __builtin_amdgcn_s_barrier();
    __builtin_amdgcn_sched_barrier(0);
  }

  // tail tile KT-2 (slot 0): no staging
  TAIL_TILE((KT - 2) & 1);
  if (SIDECAR) {
    SIDE_PACK_STORE(KT - 2);
    SIDE_LOAD(KT - 1);
    __builtin_amdgcn_sched_barrier(0);
    asm volatile("s_waitcnt vmcnt(3)" ::: "memory");  // drain stage(KT-1)
  } else {
    asm volatile("s_waitcnt vmcnt(0)" ::: "memory");
  }
  __builtin_amdgcn_s_barrier();
  __builtin_amdgcn_sched_barrier(0);

  // tail tile KT-1 (slot 1): no staging, no boundary
  TAIL_TILE((KT - 1) & 1);
  if (SIDECAR) SIDE_PACK_STORE(KT - 1);

  GEMM_EPILOGUE(bias != nullptr)
}

// ---------------- LN + activation from bf16 C + partials -> bf16 ------------
// mode 0: relu(ln)+eps ; mode 1: (relu(ln)+eps)*mask ; mode 2: ln*mask
__global__ __launch_bounds__(256) void ln_act_k(
    const unsigned short* __restrict__ Cb,
    const float* __restrict__ psum, const float* __restrict__ psq,
    const float* __restrict__ gamma, const float* __restrict__ beta,
    const float* __restrict__ mask,
    unsigned short* __restrict__ out, int mode) {
  int row = blockIdx.x;
  int t = threadIdx.x;
  float s = 0.f, s2 = 0.f;
  #pragma unroll
  for (int i = 0; i < 16; ++i) { s += psum[row * 16 + i]; s2 += psq[row * 16 + i]; }
  float mean = s * (1.f / D_MODEL);
  float var = s2 * (1.f / D_MODEL) - mean * mean;
  float rstd = rsqrtf(var + EPS_LN_F);
  float mk = (mode > 0) ? mask[row] : 1.f;
  ushort4 cv = ((const ushort4*)(Cb + (size_t)row * D_MODEL))[t];
  float4 gv = ((const float4*)gamma)[t];
  float4 bv = ((const float4*)beta)[t];
  float av[4] = {bf2f(cv.x), bf2f(cv.y), bf2f(cv.z), bf2f(cv.w)};
  float g4[4] = {gv.x, gv.y, gv.z, gv.w};
  float b4[4] = {bv.x, bv.y, bv.z, bv.w};
  unsigned short ov[4];
  #pragma unroll
  for (int j = 0; j < 4; ++j) {
    float ln = (av[j] - mean) * rstd * g4[j] + b4[j];
    if (mode == 0)      ln = fmaxf(ln, 0.f) + EPS_K_F;
    else if (mode == 1) ln = (fmaxf(ln, 0.f) + EPS_K_F) * mk;
    else                ln = ln * mk;
    ov[j] = f2bf(ln);
  }
  ushort4 o; o.x = ov[0]; o.y = ov[1]; o.z = ov[2]; o.w = ov[3];
  ((ushort4*)(out + (size_t)row * D_MODEL))[t] = o;
}

// ---------------- final LayerNorm from bf16 C + partials -> f32 out ---------
__global__ __launch_bounds__(256) void ln_final_k(
    const unsigned short* __restrict__ Cb,
    const float* __restrict__ psum, const float* __restrict__ psq,
    const float* __restrict__ gamma, const float* __restrict__ beta,
    float* __restrict__ out) {
  int row = blockIdx.x;
  int t = threadIdx.x;
  float s = 0.f, s2 = 0.f;
  #pragma unroll
  for (int i = 0; i < 16; ++i) { s += psum[row * 16 + i]; s2 += psq[row * 16 + i]; }
  float mean = s * (1.f / D_MODEL);
  float var = s2 * (1.f / D_MODEL) - mean * mean;
  float rstd = rsqrtf(var + EPS_LN_F);
  ushort4 cv = ((const ushort4*)(Cb + (size_t)row * D_MODEL))[t];
  float4 gv = ((const float4*)gamma)[t];
  float4 bv = ((const float4*)beta)[t];
  float4 w;
  w.x = (bf2f(cv.x) - mean) * rstd * gv.x + bv.x;
  w.y = (bf2f(cv.y) - mean) * rstd * gv.y + bv.y;
  w.z = (bf2f(cv.z) - mean) * rstd * gv.z + bv.z;
  w.w = (bf2f(cv.w) - mean) * rstd * gv.w + bv.w;
  ((float4*)(out + (size_t)row * D_MODEL))[t] = w;
}

// ---------------- KV via MFMA with swizzled-LDS transpose -------------------
__global__ __launch_bounds__(256) void kv_mfma_k(
    const unsigned short* __restrict__ Kp, const unsigned short* __restrict__ Vp,
    float* __restrict__ part, float* __restrict__ kspart) {
  __shared__ unsigned short Kl[4096];
  __shared__ unsigned short Vl[4096];
  int bh = blockIdx.y, chunk = blockIdx.x;   // chunk 0..7, 512 n each
  int b_ = bh >> 4, h = bh & 15;
  int t = threadIdx.x, lane = t & 63, w = t >> 6;
  int l15 = lane & 15, g = lane >> 4;        // g in 0..3

  int sn = t >> 2, sd16 = t & 3;
  int sc = sd16 ^ ((sn >> 3) & 3);
  size_t goff = (size_t)sn * D_MODEL + h * DEPTH + sd16 * 16;
  int ldst = sn * 64 + sc * 16;

  short8 ones;
  #pragma unroll
  for (int i = 0; i < 8; ++i) ones[i] = (short)0x3F80;

  f32x4 acc[4] = {};
  f32x4 ks = {};

  int baseA = ((w ^ g) << 4) + l15;
  int baseB0 = ((0 ^ g) << 4) + l15;
  int baseB1 = ((1 ^ g) << 4) + l15;
  int baseB2 = ((2 ^ g) << 4) + l15;
  int baseB3 = ((3 ^ g) << 4) + l15;

  size_t rowbase = ((size_t)b_ * S_LEN + (size_t)chunk * 512) * D_MODEL;
  for (int tile = 0; tile < 8; ++tile) {
    const unsigned short* kg = Kp + rowbase + (size_t)tile * 64 * D_MODEL + goff;
    const unsigned short* vg = Vp + rowbase + (size_t)tile * 64 * D_MODEL + goff;
    uint4 ra = *(const uint4*)kg;
    uint4 rb = *(const uint4*)(kg + 8);
    uint4 rc = *(const uint4*)vg;
    uint4 rd = *(const uint4*)(vg + 8);
    __syncthreads();
    *(uint4*)&Kl[ldst]     = ra;
    *(uint4*)&Kl[ldst + 8] = rb;
    *(uint4*)&Vl[ldst]     = rc;
    *(uint4*)&Vl[ldst + 8] = rd;
    __syncthreads();
    #pragma unroll
    for (int kk = 0; kk < 2; ++kk) {
      int nb = (kk * 32 + g * 8) * 64;
      short8 af, bf0, bf1, bf2, bf3;
      #pragma unroll
      for (int i = 0; i < 8; ++i) {
        int rowoff = nb + i * 64;
        af[i]  = (short)Kl[rowoff + baseA];
        bf0[i] = (short)Vl[rowoff + baseB0];
        bf1[i] = (short)Vl[rowoff + baseB1];
        bf2[i] = (short)Vl[rowoff + baseB2];
        bf3[i] = (short)Vl[rowoff + baseB3];
      }
      acc[0] = __builtin_amdgcn_mfma_f32_16x16x32_bf16(af, bf0, acc[0], 0, 0, 0);
      acc[1] = __builtin_amdgcn_mfma_f32_16x16x32_bf16(af, bf1, acc[1], 0, 0, 0);
      acc[2] = __builtin_amdgcn_mfma_f32_16x16x32_bf16(af, bf2, acc[2], 0, 0, 0);
      acc[3] = __builtin_amdgcn_mfma_f32_16x16x32_bf16(af, bf3, acc[3], 0, 0, 0);
      ks     = __builtin_amdgcn_mfma_f32_16x16x32_bf16(af, ones, ks, 0, 0, 0);
    }
  }
  float* pp = part + ((size_t)bh * 8 + chunk) * 4096;
  #pragma unroll
  for (int nf = 0; nf < 4; ++nf)
    #pragma unroll
    for (int r = 0; r < 4; ++r)
      pp[(16 * w + 4 * g + r) * 64 + 16 * nf + l15] = acc[nf][r];
  if (l15 == 0) {
    #pragma unroll
    for (int r = 0; r < 4; ++r)
      kspart[((size_t)bh * 8 + chunk) * 64 + 16 * w + 4 * g + r] = ks[r];
  }
}

// ---------------- KV reduce -> KV^T bf16 ([e][d]) + ksum f32 ----------------
__global__ __launch_bounds__(256) void kv_reduce_k(
    const float* __restrict__ part, const float* __restrict__ kspart,
    unsigned short* __restrict__ KVT, float* __restrict__ ksum) {
  int bh = blockIdx.x, t = threadIdx.x;
  for (int idx = t; idx < 4096; idx += 256) {
    int d = idx >> 6, e = idx & 63;
    float s = 0.f;
    #pragma unroll
    for (int c = 0; c < 8; ++c)
      s += part[((size_t)bh * 8 + c) * 4096 + d * 64 + e];
    KVT[(size_t)bh * 4096 + e * 64 + d] = f2bf(s);
  }
  if (t < 64) {
    float s = 0.f;
    #pragma unroll
    for (int c = 0; c < 8; ++c) s += kspart[((size_t)bh * 8 + c) * 64 + t];
    ksum[bh * 64 + t] = s;
  }
}

// ---------------- att = (q' @ KV) * z, written in the reference's reshape ---
__global__ __launch_bounds__(256) void att_k(
    const unsigned short* __restrict__ Qp, const unsigned short* __restrict__ KVT,
    const float* __restrict__ ksum, unsigned short* __restrict__ att) {
  __shared__ unsigned short Ql[128 * 64];
  __shared__ unsigned short Kl[64 * 64];
  __shared__ float ksl[64];
  __shared__ float zl[128];
  int bh = blockIdx.y;
  int b = bh >> 4, h = bh & 15;
  int r0 = blockIdx.x * 128;
  int t = threadIdx.x, lane = t & 63, wid = t >> 6;
  int l15 = lane & 15, lhi = lane >> 4;
  #pragma unroll
  for (int i = 0; i < 4; ++i) {
    int cid = i * 256 + t;
    int r = cid >> 3, c8 = cid & 7;
    gload16(Qp + ((size_t)(b * S_LEN + r0 + r)) * D_MODEL + h * DEPTH + c8 * 8,
            &Ql[cid * 8]);
  }
  #pragma unroll
  for (int i = 0; i < 2; ++i) {
    int cid = i * 256 + t;
    gload16(KVT + (size_t)bh * 4096 + cid * 8, &Kl[cid * 8]);
  }
  if (t < 64) ksl[t] = ksum[bh * 64 + t];
  asm volatile("s_waitcnt vmcnt(0)" ::: "memory");
  __syncthreads();
  {
    int r = t >> 1, half = t & 1;
    float s = 0.f;
    #pragma unroll
    for (int j = 0; j < 32; ++j)
      s += bf2f(Ql[r * 64 + half * 32 + j]) * ksl[half * 32 + j];
    s += __shfl_xor(s, 1);
    if (half == 0) zl[r] = 1.f / (s + EPS_K_F);
  }
  __syncthreads();
  f32x4 acc[2][4] = {};
  #pragma unroll
  for (int kk = 0; kk < 2; ++kk) {
    short8 af[2], bfr[4];
    #pragma unroll
    for (int m = 0; m < 2; ++m)
      af[m] = *(const short8*)&Ql[(wid * 32 + m * 16 + l15) * 64 + kk * 32 + lhi * 8];
    #pragma unroll
    for (int n = 0; n < 4; ++n)
      bfr[n] = *(const short8*)&Kl[(n * 16 + l15) * 64 + kk * 32 + lhi * 8];
    #pragma unroll
    for (int m = 0; m < 2; ++m)
      #pragma unroll
      for (int n = 0; n < 4; ++n)
        acc[m][n] = __builtin_amdgcn_mfma_f32_16x16x32_bf16(af[m], bfr[n], acc[m][n], 0, 0, 0);
  }
  #pragma unroll
  for (int m = 0; m < 2; ++m)
    #pragma unroll
    for (int j = 0; j < 4; ++j) {
      int rl = wid * 32 + m * 16 + lhi * 4 + j;
      int n = r0 + rl;
      float z = zl[rl];
      #pragma unroll
      for (int nf = 0; nf < 4; ++nf) {
        int ee = nf * 16 + l15;
        size_t orow = (size_t)b * S_LEN + h * 256 + (n >> 4);
        int ocol = (n & 15) * 64 + ee;
        att[orow * D_MODEL + ocol] = f2bf(acc[m][nf][j] * z);
      }
    }
}

extern "C" void kernel_launch(void* const* d_in, const int* in_sizes, int n_in,
                              void* d_out, int out_size, void* d_ws, size_t ws_size,
                              hipStream_t stream) {
  (void)in_sizes; (void)n_in; (void)out_size; (void)ws_size;
  const float* q     = (const float*)d_in[0];
  const float* k     = (const float*)d_in[1];
  const float* v     = (const float*)d_in[2];
  const float* mask  = (const float*)d_in[3];
  const float* wq    = (const float*)d_in[4];
  const float* wk    = (const float*)d_in[5];
  const float* wv    = (const float*)d_in[6];
  const float* gamma = (const float*)d_in[7];
  const float* beta  = (const float*)d_in[8];
  const float* dw    = (const float*)d_in[9];
  const float* db    = (const float*)d_in[10];
  float* out = (float*)d_out;

  char* ws = (char*)d_ws;
  // buffer plan (lifetimes hand-verified):
  //   ws+0   : Xq (wtrans sidecar) -> dead after gemm_q -> Qp (ln_act)
  //            -> dead after att -> Cd (dense C).
  //   ws+32M : Xk (gemm_q sidecar) -> dead after gemm_k -> Kp (ln_act)
  //            -> dead after kv_mfma.
  //   ws+64M : Xv (gemm_k sidecar) -> dead after gemm_v -> Vp (ln_act)
  //            -> dead after kv_mfma.
  //   ws+96M : weights; ws+104M: part; ws+112M: kspart/KVT/ksum; psum/psq.
  //   d_out  : bf16 C scratch for q/k/v GEMMs + att output (first 32 MB),
  //            fully overwritten by ln_final at the end.
  unsigned short* Xq  = (unsigned short*)(ws);
  unsigned short* Xk  = (unsigned short*)(ws + 33554432);
  unsigned short* Xv  = (unsigned short*)(ws + 67108864);
  unsigned short* Qp  = Xq;
  unsigned short* Kp  = Xk;
  unsigned short* Vp  = Xv;
  unsigned short* Cd  = Xq;                 // dense C after att consumed Qp
  unsigned short* WqT = (unsigned short*)(ws + 100663296);
  unsigned short* WkT = WqT + 1048576;
  unsigned short* WvT = WkT + 1048576;
  unsigned short* WdT = WvT + 1048576;
  float* part   = (float*)(ws + 109051904);
  float* kspart = (float*)(ws + 117440512);
  unsigned short* KVT = (unsigned short*)(ws + 117964800);
  float* ksum = (float*)(ws + 118489088);
  float* psum = (float*)(ws + 119537664);   // 1 MB
  float* psq  = (float*)(ws + 120586240);   // 1 MB
  unsigned short* Cqkv = (unsigned short*)d_out;   // bf16 C scratch / att out

  dim3 b256(256);
  dim3 b512(512);
  dim3 wtg(32, 32);
  dim3 gemmg(256);            // (M/256)*(N/256), XCD-swizzled in-kernel
  dim3 lng(ROWS);

  // wtrans x4, each also converting a quarter of q -> Xq
  wtrans_k<<<wtg, b256, 0, stream>>>(wq, WqT, q, Xq, 0);
  wtrans_k<<<wtg, b256, 0, stream>>>(wk, WkT, q, Xq, 1);
  wtrans_k<<<wtg, b256, 0, stream>>>(wv, WvT, q, Xq, 2);
  wtrans_k<<<wtg, b256, 0, stream>>>(dw, WdT, q, Xq, 3);

  // gemm_q: sidecar converts k -> Xk
  gemm_bt_k<true><<<gemmg, b512, 0, stream>>>(Xq, WqT, Cqkv, psum, psq, nullptr,
                                              k, Xk, ROWS, D_MODEL, D_MODEL);
  ln_act_k<<<lng, b256, 0, stream>>>(Cqkv, psum, psq, gamma, beta, nullptr, Qp, 0);

  // gemm_k: sidecar converts v -> Xv
  gemm_bt_k<true><<<gemmg, b512, 0, stream>>>(Xk, WkT, Cqkv, psum, psq, nullptr,
                                              v, Xv, ROWS, D_MODEL, D_MODEL);
  ln_act_k<<<lng, b256, 0, stream>>>(Cqkv, psum, psq, gamma, beta, mask, Kp, 1);

  gemm_bt_k<false><<<gemmg, b512, 0, stream>>>(Xv, WvT, Cqkv, psum, psq, nullptr,
                                               nullptr, nullptr, ROWS, D_MODEL, D_MODEL);
  ln_act_k<<<lng, b256, 0, stream>>>(Cqkv, psum, psq, gamma, beta, mask, Vp, 2);

  kv_mfma_k<<<dim3(8, 64), b256, 0, stream>>>(Kp, Vp, part, kspart);
  kv_reduce_k<<<dim3(64), b256, 0, stream>>>(part, kspart, KVT, ksum);
  att_k<<<dim3(32, 64), b256, 0, stream>>>(Qp, KVT, ksum, Cqkv);

  gemm_bt_k<false><<<gemmg, b512, 0, stream>>>(Cqkv, WdT, Cd, psum, psq, db,
                                               nullptr, nullptr, ROWS, D_MODEL, D_MODEL);
  ln_final_k<<<lng, b256, 0, stream>>>(Cd, psum, psq, gamma, beta, out);
}

// Round 16
// 310.945 us; speedup vs baseline: 1.5696x; 1.0803x over previous
//
#include <hip/hip_runtime.h>
#include <hip/hip_bf16.h>
#include <stdint.h>

#define D_MODEL 1024
#define S_LEN   4096
#define BATCH   4
#define HEADS   16
#define DEPTH   64
#define ROWS    (BATCH*S_LEN)   // 16384
#define EPS_K_F 1e-6f
#define EPS_LN_F 1e-6f

typedef __attribute__((ext_vector_type(8))) short short8;
typedef __attribute__((ext_vector_type(4))) float f32x4;

__device__ __forceinline__ unsigned short f2bf(float f) {
  union { float f; unsigned u; } x; x.f = f;
  unsigned r = x.u + 0x7FFF + ((x.u >> 16) & 1);
  return (unsigned short)(r >> 16);
}
__device__ __forceinline__ float bf2f(unsigned short b) {
  union { unsigned u; float f; } x; x.u = ((unsigned)b) << 16;
  return x.f;
}
__device__ __forceinline__ void gload16(const void* g, void* l) {
  __builtin_amdgcn_global_load_lds(
      (const __attribute__((address_space(1))) void*)g,
      (__attribute__((address_space(3))) void*)l, 16, 0, 0);
}

// -------- weight transpose + convert, with q-conversion sidecar -------------
__global__ __launch_bounds__(256) void wtrans_k(
    const float* __restrict__ W, unsigned short* __restrict__ Wt,
    const float* __restrict__ qsrc, unsigned short* __restrict__ qdst,
    int slice) {
  __shared__ float tile[32][33];
  int n0 = blockIdx.x * 32, k0 = blockIdx.y * 32;
  int tx = threadIdx.x & 31, ty = threadIdx.x >> 5;
  #pragma unroll
  for (int i = 0; i < 32; i += 8)
    tile[ty + i][tx] = W[(size_t)(k0 + ty + i) * D_MODEL + n0 + tx];
  if (qsrc) {
    int bid = blockIdx.y * 32 + blockIdx.x;
    size_t base = (size_t)slice * 4194304 + (size_t)bid * 4096 +
                  (size_t)threadIdx.x * 8;
    #pragma unroll
    for (int it = 0; it < 2; ++it) {
      size_t off = base + (size_t)it * 2048;
      float4 a = *(const float4*)(qsrc + off);
      float4 b = *(const float4*)(qsrc + off + 4);
      uint4 pk;
      pk.x = (unsigned)f2bf(a.x) | ((unsigned)f2bf(a.y) << 16);
      pk.y = (unsigned)f2bf(a.z) | ((unsigned)f2bf(a.w) << 16);
      pk.z = (unsigned)f2bf(b.x) | ((unsigned)f2bf(b.y) << 16);
      pk.w = (unsigned)f2bf(b.z) | ((unsigned)f2bf(b.w) << 16);
      *(uint4*)(qdst + off) = pk;
    }
  }
  __syncthreads();
  #pragma unroll
  for (int i = 0; i < 32; i += 8)
    Wt[(size_t)(n0 + ty + i) * D_MODEL + k0 + tx] = f2bf(tile[tx][ty + i]);
}

// ===== GEMM: 256x256 tile, 8 waves, BK=64, counted-vmcnt 4-phase pipeline ===
// (identical core to R15; conflict-free swizzle slot = chunk ^ ((row>>1)&3))

#define GEMM_EPILOGUE(HASBIAS)                                               \
  if (HASBIAS) {                                                             \
    float bv[4];                                                             \
    _Pragma("unroll")                                                        \
    for (int n = 0; n < 4; ++n)                                              \
      bv[n] = bias[(int)n0 + wcn * 64 + n * 16 + l15];                       \
    _Pragma("unroll")                                                        \
    for (int m = 0; m < 8; ++m)                                              \
      _Pragma("unroll")                                                      \
      for (int n = 0; n < 4; ++n)                                            \
        _Pragma("unroll")                                                    \
        for (int j = 0; j < 4; ++j)                                          \
          acc[m][n][j] += bv[n];                                             \
  }                                                                          \
  int seg = (int)(n0 >> 6) + wcn;                                            \
  _Pragma("unroll")                                                          \
  for (int m = 0; m < 8; ++m) {                                              \
    float s[4], s2[4];                                                       \
    _Pragma("unroll")                                                        \
    for (int j = 0; j < 4; ++j) {                                            \
      float a = 0.f, b = 0.f;                                                \
      _Pragma("unroll")                                                      \
      for (int n = 0; n < 4; ++n) { float x = acc[m][n][j]; a += x; b += x*x; } \
      s[j] = a; s2[j] = b;                                                   \
    }                                                                        \
    _Pragma("unroll")                                                        \
    for (int off = 1; off < 16; off <<= 1) {                                 \
      _Pragma("unroll")                                                      \
      for (int j = 0; j < 4; ++j) {                                          \
        s[j]  += __shfl_xor(s[j],  off);                                     \
        s2[j] += __shfl_xor(s2[j], off);                                     \
      }                                                                      \
    }                                                                        \
    if (l15 == 0) {                                                          \
      _Pragma("unroll")                                                      \
      for (int j = 0; j < 4; ++j) {                                          \
        int rg = (int)m0 + wr * 128 + m * 16 + lhi * 4 + j;                  \
        psum[rg * 16 + seg] = s[j];                                          \
        psq [rg * 16 + seg] = s2[j];                                         \
      }                                                                      \
    }                                                                        \
  }                                                                          \
  _Pragma("unroll")                                                          \
  for (int m = 0; m < 8; ++m)                                                \
    _Pragma("unroll")                                                        \
    for (int j = 0; j < 4; ++j) {                                            \
      size_t row = m0 + wr * 128 + m * 16 + lhi * 4 + j;                     \
      _Pragma("unroll")                                                      \
      for (int n = 0; n < 4; ++n) {                                          \
        int col = (int)n0 + wcn * 64 + n * 16 + l15;                         \
        Cb[row * N + col] = f2bf(acc[m][n][j]);                              \
      }                                                                      \
    }

#define STAGE_HALF(kof_, slot_, h_) do {                                     \
    _Pragma("unroll")                                                        \
    for (int j = 0; j < 2; ++j) {                                            \
      int idx = j * 512 + t; int r_ = idx >> 2; int cs_ = idx & 3;           \
      int c_ = cs_ ^ ((r_ >> 1) & 3);                                        \
      gload16(A + (m0 + r_) * (size_t)K + (kof_) + (h_) * 32 + c_ * 8,       \
              &Al[slot_][(h_) * 8192 + idx * 8]);                            \
    }                                                                        \
    _Pragma("unroll")                                                        \
    for (int j = 0; j < 2; ++j) {                                            \
      int idx = j * 512 + t; int r_ = idx >> 2; int cs_ = idx & 3;           \
      int c_ = cs_ ^ ((r_ >> 1) & 3);                                        \
      gload16(Bt + (n0 + r_) * (size_t)K + (kof_) + (h_) * 32 + c_ * 8,      \
              &Bl[slot_][(h_) * 8192 + idx * 8]);                            \
    }                                                                        \
  } while (0)

#define PH_READ_B(kk_)                                                       \
    _Pragma("unroll")                                                        \
    for (int n = 0; n < 4; ++n) {                                            \
      int rb_ = wcn * 64 + n * 16 + l15;                                     \
      bfr[n] = *(const short8*)&Bl[slot][(kk_) * 8192 + rb_ * 32 + cswz];    \
    }
#define PH_READ_A(kk_, mh_)                                                  \
    _Pragma("unroll")                                                        \
    for (int m = 0; m < 4; ++m) {                                            \
      int ra_ = wr * 128 + ((mh_) * 4 + m) * 16 + l15;                       \
      af[m] = *(const short8*)&Al[slot][(kk_) * 8192 + ra_ * 32 + cswz];     \
    }
#define PH_MFMA(mh_)                                                         \
    __builtin_amdgcn_s_setprio(1);                                           \
    _Pragma("unroll")                                                        \
    for (int m = 0; m < 4; ++m)                                              \
      _Pragma("unroll")                                                      \
      for (int n = 0; n < 4; ++n)                                            \
        acc[(mh_) * 4 + m][n] = __builtin_amdgcn_mfma_f32_16x16x32_bf16(     \
            af[m], bfr[n], acc[(mh_) * 4 + m][n], 0, 0, 0);                  \
    __builtin_amdgcn_s_setprio(0);
#define LGKM0                                                                \
    asm volatile("s_waitcnt lgkmcnt(0)" ::: "memory");                       \
    __builtin_amdgcn_sched_barrier(0);

#define SIDE_PACK_STORE(chunk_) do {                                         \
    uint4 pk_;                                                               \
    pk_.x = (unsigned)f2bf(sreg0.x) | ((unsigned)f2bf(sreg0.y) << 16);       \
    pk_.y = (unsigned)f2bf(sreg0.z) | ((unsigned)f2bf(sreg0.w) << 16);       \
    pk_.z = (unsigned)f2bf(sreg1.x) | ((unsigned)f2bf(sreg1.y) << 16);       \
    pk_.w = (unsigned)f2bf(sreg1.z) | ((unsigned)f2bf(sreg1.w) << 16);       \
    *(uint4*)(side_dst + sbase + (size_t)(chunk_) * 4096) = pk_;             \
  } while (0)
#define SIDE_LOAD(chunk_) do {                                               \
    const float* sp_ = side_src + sbase + (size_t)(chunk_) * 4096;           \
    sreg0 = *(const float4*)sp_; sreg1 = *(const float4*)(sp_ + 4);          \
  } while (0)

#define TAIL_TILE(slot_) do {                                                \
    const int slot = (slot_);                                                \
    short8 af[4], bfr[4];                                                    \
    PH_READ_B(0) PH_READ_A(0, 0) LGKM0 PH_MFMA(0)                            \
    PH_READ_A(0, 1) LGKM0 PH_MFMA(1)                                         \
    PH_READ_B(1) PH_READ_A(1, 0) LGKM0 PH_MFMA(0)                            \
    PH_READ_A(1, 1) LGKM0 PH_MFMA(1)                                         \
  } while (0)

template <bool SIDECAR>
__global__ __launch_bounds__(512) void gemm_bt_k(
    const unsigned short* __restrict__ A,
    const unsigned short* __restrict__ Bt,
    unsigned short* __restrict__ Cb,
    float* __restrict__ psum, float* __restrict__ psq,
    const float* __restrict__ bias,
    const float* __restrict__ side_src,
    unsigned short* __restrict__ side_dst,
    int M, int N, int K) {
  __shared__ unsigned short Al[2][16384];
  __shared__ unsigned short Bl[2][16384];
  int t = threadIdx.x;
  int lane = t & 63, wid = t >> 6;
  int wr = wid >> 2, wcn = wid & 3;
  int l15 = lane & 15, lhi = lane >> 4;
  const int cswz = (lhi ^ ((l15 >> 1) & 3)) << 3;
  int p = blockIdx.x;
  int cb = (p >> 3) & 3;
  int rb = (p & 7) | ((p >> 5) << 3);
  size_t m0 = (size_t)rb * 256, n0 = (size_t)cb * 256;
  f32x4 acc[8][4] = {};

  const int KT = K >> 6;

  float4 sreg0 = {}, sreg1 = {};
  size_t sbase = (size_t)p * 65536 + (size_t)t * 8;

  if (SIDECAR) SIDE_LOAD(0);
  STAGE_HALF(0, 0, 0);  STAGE_HALF(0, 0, 1);
  STAGE_HALF(64, 1, 0); STAGE_HALF(64, 1, 1);
  asm volatile("s_waitcnt vmcnt(8)" ::: "memory");
  __builtin_amdgcn_s_barrier();
  __builtin_amdgcn_sched_barrier(0);

  for (int kt = 0; kt < KT - 2; ++kt) {
    const int slot = kt & 1;
    short8 af[4], bfr[4];
    PH_READ_B(0)
    PH_READ_A(0, 0)
    LGKM0
    PH_MFMA(0)
    PH_READ_A(0, 1)
    LGKM0
    __builtin_amdgcn_s_barrier();
    __builtin_amdgcn_sched_barrier(0);
    STAGE_HALF((kt + 2) << 6, slot, 0);
    __builtin_amdgcn_sched_barrier(0);
    PH_MFMA(1)
    PH_READ_B(1)
    PH_READ_A(1, 0)
    LGKM0
    PH_MFMA(0)
    PH_READ_A(1, 1)
    LGKM0
    __builtin_amdgcn_s_barrier();
    __builtin_amdgcn_sched_barrier(0);
    STAGE_HALF((kt + 2) << 6, slot, 1);
    __builtin_amdgcn_sched_barrier(0);
    PH_MFMA(1)
    if (SIDECAR) {
      SIDE_PACK_STORE(kt);
      SIDE_LOAD(kt + 1);
      __builtin_amdgcn_sched_barrier(0);
      asm volatile("s_waitcnt vmcnt(11)" ::: "memory");
    } else {
      asm volatile("s_waitcnt vmcnt(8)" ::: "memory");
    }
    __builtin_amdgcn_s_barrier();
    __builtin_amdgcn_sched_barrier(0);
  }

  TAIL_TILE((KT - 2) & 1);
  if (SIDECAR) {
    SIDE_PACK_STORE(KT - 2);
    SIDE_LOAD(KT - 1);
    __builtin_amdgcn_sched_barrier(0);
    asm volatile("s_waitcnt vmcnt(3)" ::: "memory");
  } else {
    asm volatile("s_waitcnt vmcnt(0)" ::: "memory");
  }
  __builtin_amdgcn_s_barrier();
  __builtin_amdgcn_sched_barrier(0);

  TAIL_TILE((KT - 1) & 1);
  if (SIDECAR) SIDE_PACK_STORE(KT - 1);

  GEMM_EPILOGUE(bias != nullptr)
}

// ---------------- LN stats: per-row mean/rstd from partials (K and V) -------
__global__ __launch_bounds__(256) void ln_stats_k(
    const float* __restrict__ psumK, const float* __restrict__ psqK,
    const float* __restrict__ psumV, const float* __restrict__ psqV,
    float* __restrict__ meanK, float* __restrict__ rstdK,
    float* __restrict__ meanV, float* __restrict__ rstdV) {
  int row = blockIdx.x * 256 + threadIdx.x;
  float sK = 0.f, s2K = 0.f, sV = 0.f, s2V = 0.f;
  #pragma unroll
  for (int i = 0; i < 16; ++i) {
    sK += psumK[row * 16 + i]; s2K += psqK[row * 16 + i];
    sV += psumV[row * 16 + i]; s2V += psqV[row * 16 + i];
  }
  float mK = sK * (1.f / D_MODEL);
  float mV = sV * (1.f / D_MODEL);
  meanK[row] = mK;
  rstdK[row] = rsqrtf(s2K * (1.f / D_MODEL) - mK * mK + EPS_LN_F);
  meanV[row] = mV;
  rstdV[row] = rsqrtf(s2V * (1.f / D_MODEL) - mV * mV + EPS_LN_F);
}

// ---------------- LN + activation from bf16 C + partials -> bf16 (Q only) ---
__global__ __launch_bounds__(256) void ln_act_k(
    const unsigned short* __restrict__ Cb,
    const float* __restrict__ psum, const float* __restrict__ psq,
    const float* __restrict__ gamma, const float* __restrict__ beta,
    unsigned short* __restrict__ out) {
  int row = blockIdx.x;
  int t = threadIdx.x;
  float s = 0.f, s2 = 0.f;
  #pragma unroll
  for (int i = 0; i < 16; ++i) { s += psum[row * 16 + i]; s2 += psq[row * 16 + i]; }
  float mean = s * (1.f / D_MODEL);
  float var = s2 * (1.f / D_MODEL) - mean * mean;
  float rstd = rsqrtf(var + EPS_LN_F);
  ushort4 cv = ((const ushort4*)(Cb + (size_t)row * D_MODEL))[t];
  float4 gv = ((const float4*)gamma)[t];
  float4 bv = ((const float4*)beta)[t];
  float av[4] = {bf2f(cv.x), bf2f(cv.y), bf2f(cv.z), bf2f(cv.w)};
  float g4[4] = {gv.x, gv.y, gv.z, gv.w};
  float b4[4] = {bv.x, bv.y, bv.z, bv.w};
  unsigned short ov[4];
  #pragma unroll
  for (int j = 0; j < 4; ++j) {
    float ln = (av[j] - mean) * rstd * g4[j] + b4[j];
    ov[j] = f2bf(fmaxf(ln, 0.f) + EPS_K_F);
  }
  ushort4 o; o.x = ov[0]; o.y = ov[1]; o.z = ov[2]; o.w = ov[3];
  ((ushort4*)(out + (size_t)row * D_MODEL))[t] = o;
}

// ---------------- final LayerNorm from bf16 C + partials -> f32 out ---------
__global__ __launch_bounds__(256) void ln_final_k(
    const unsigned short* __restrict__ Cb,
    const float* __restrict__ psum, const float* __restrict__ psq,
    const float* __restrict__ gamma, const float* __restrict__ beta,
    float* __restrict__ out) {
  int row = blockIdx.x;
  int t = threadIdx.x;
  float s = 0.f, s2 = 0.f;
  #pragma unroll
  for (int i = 0; i < 16; ++i) { s += psum[row * 16 + i]; s2 += psq[row * 16 + i]; }
  float mean = s * (1.f / D_MODEL);
  float var = s2 * (1.f / D_MODEL) - mean * mean;
  float rstd = rsqrtf(var + EPS_LN_F);
  ushort4 cv = ((const ushort4*)(Cb + (size_t)row * D_MODEL))[t];
  float4 gv = ((const float4*)gamma)[t];
  float4 bv = ((const float4*)beta)[t];
  float4 w;
  w.x = (bf2f(cv.x) - mean) * rstd * gv.x + bv.x;
  w.y = (bf2f(cv.y) - mean) * rstd * gv.y + bv.y;
  w.z = (bf2f(cv.z) - mean) * rstd * gv.z + bv.z;
  w.w = (bf2f(cv.w) - mean) * rstd * gv.w + bv.w;
  ((float4*)(out + (size_t)row * D_MODEL))[t] = w;
}

// ---------------- KV via MFMA, with fused LN+activation on staging ----------
// Reads RAW GEMM outputs Ck, Cv; applies K' = (relu(ln)+eps)*mask and
// V' = ln*mask per element between register load and swizzled LDS write.
__global__ __launch_bounds__(256) void kv_mfma_k(
    const unsigned short* __restrict__ Ck, const unsigned short* __restrict__ Cv,
    const float* __restrict__ meanK, const float* __restrict__ rstdK,
    const float* __restrict__ meanV, const float* __restrict__ rstdV,
    const float* __restrict__ mask,
    const float* __restrict__ gamma, const float* __restrict__ beta,
    float* __restrict__ part, float* __restrict__ kspart) {
  __shared__ unsigned short Kl[4096];
  __shared__ unsigned short Vl[4096];
  int bh = blockIdx.y, chunk = blockIdx.x;   // chunk 0..7, 512 n each
  int b_ = bh >> 4, h = bh & 15;
  int t = threadIdx.x, lane = t & 63, w = t >> 6;
  int l15 = lane & 15, g = lane >> 4;

  int sn = t >> 2, sd16 = t & 3;
  int sc = sd16 ^ ((sn >> 3) & 3);
  size_t goff = (size_t)sn * D_MODEL + h * DEPTH + sd16 * 16;
  int ldst = sn * 64 + sc * 16;

  // hoist gamma/beta for this thread's fixed 16-col group
  float g16[16], b16[16];
  {
    int cbase = h * DEPTH + sd16 * 16;
    #pragma unroll
    for (int i = 0; i < 4; ++i) {
      float4 gv = *(const float4*)(gamma + cbase + i * 4);
      float4 bv = *(const float4*)(beta + cbase + i * 4);
      g16[i*4+0] = gv.x; g16[i*4+1] = gv.y; g16[i*4+2] = gv.z; g16[i*4+3] = gv.w;
      b16[i*4+0] = bv.x; b16[i*4+1] = bv.y; b16[i*4+2] = bv.z; b16[i*4+3] = bv.w;
    }
  }

  short8 ones;
  #pragma unroll
  for (int i = 0; i < 8; ++i) ones[i] = (short)0x3F80;

  f32x4 acc[4] = {};
  f32x4 ks = {};

  int baseA = ((w ^ g) << 4) + l15;
  int baseB0 = ((0 ^ g) << 4) + l15;
  int baseB1 = ((1 ^ g) << 4) + l15;
  int baseB2 = ((2 ^ g) << 4) + l15;
  int baseB3 = ((3 ^ g) << 4) + l15;

  int rowbase_r = b_ * S_LEN + chunk * 512;
  size_t rowbase = (size_t)rowbase_r * D_MODEL;
  for (int tile = 0; tile < 8; ++tile) {
    const unsigned short* kg = Ck + rowbase + (size_t)tile * 64 * D_MODEL + goff;
    const unsigned short* vg = Cv + rowbase + (size_t)tile * 64 * D_MODEL + goff;
    uint4 ra = *(const uint4*)kg;
    uint4 rb = *(const uint4*)(kg + 8);
    uint4 rc = *(const uint4*)vg;
    uint4 rd = *(const uint4*)(vg + 8);
    int grow = rowbase_r + tile * 64 + sn;
    float mk  = mask[grow];
    float mKv = meanK[grow], rKv = rstdK[grow];
    float mVv = meanV[grow], rVv = rstdV[grow];
    // unpack-transform-repack (16 elems per tensor)
    union { uint4 u[2]; unsigned short s[16]; } kin, vin, kout, vout;
    kin.u[0] = ra; kin.u[1] = rb;
    vin.u[0] = rc; vin.u[1] = rd;
    #pragma unroll
    for (int j = 0; j < 16; ++j) {
      float lnk = (bf2f(kin.s[j]) - mKv) * rKv * g16[j] + b16[j];
      kout.s[j] = f2bf((fmaxf(lnk, 0.f) + EPS_K_F) * mk);
      float lnv = (bf2f(vin.s[j]) - mVv) * rVv * g16[j] + b16[j];
      vout.s[j] = f2bf(lnv * mk);
    }
    __syncthreads();
    *(uint4*)&Kl[ldst]     = kout.u[0];
    *(uint4*)&Kl[ldst + 8] = kout.u[1];
    *(uint4*)&Vl[ldst]     = vout.u[0];
    *(uint4*)&Vl[ldst + 8] = vout.u[1];
    __syncthreads();
    #pragma unroll
    for (int kk = 0; kk < 2; ++kk) {
      int nb = (kk * 32 + g * 8) * 64;
      short8 af, bf0, bf1, bf2, bf3;
      #pragma unroll
      for (int i = 0; i < 8; ++i) {
        int rowoff = nb + i * 64;
        af[i]  = (short)Kl[rowoff + baseA];
        bf0[i] = (short)Vl[rowoff + baseB0];
        bf1[i] = (short)Vl[rowoff + baseB1];
        bf2[i] = (short)Vl[rowoff + baseB2];
        bf3[i] = (short)Vl[rowoff + baseB3];
      }
      acc[0] = __builtin_amdgcn_mfma_f32_16x16x32_bf16(af, bf0, acc[0], 0, 0, 0);
      acc[1] = __builtin_amdgcn_mfma_f32_16x16x32_bf16(af, bf1, acc[1], 0, 0, 0);
      acc[2] = __builtin_amdgcn_mfma_f32_16x16x32_bf16(af, bf2, acc[2], 0, 0, 0);
      acc[3] = __builtin_amdgcn_mfma_f32_16x16x32_bf16(af, bf3, acc[3], 0, 0, 0);
      ks     = __builtin_amdgcn_mfma_f32_16x16x32_bf16(af, ones, ks, 0, 0, 0);
    }
  }
  float* pp = part + ((size_t)bh * 8 + chunk) * 4096;
  #pragma unroll
  for (int nf = 0; nf < 4; ++nf)
    #pragma unroll
    for (int r = 0; r < 4; ++r)
      pp[(16 * w + 4 * g + r) * 64 + 16 * nf + l15] = acc[nf][r];
  if (l15 == 0) {
    #pragma unroll
    for (int r = 0; r < 4; ++r)
      kspart[((size_t)bh * 8 + chunk) * 64 + 16 * w + 4 * g + r] = ks[r];
  }
}

// ---------------- KV reduce -> KV^T bf16 ([e][d]) + ksum f32 ----------------
__global__ __launch_bounds__(256) void kv_reduce_k(
    const float* __restrict__ part, const float* __restrict__ kspart,
    unsigned short* __restrict__ KVT, float* __restrict__ ksum) {
  int bh = blockIdx.x, t = threadIdx.x;
  for (int idx = t; idx < 4096; idx += 256) {
    int d = idx >> 6, e = idx & 63;
    float s = 0.f;
    #pragma unroll
    for (int c = 0; c < 8; ++c)
      s += part[((size_t)bh * 8 + c) * 4096 + d * 64 + e];
    KVT[(size_t)bh * 4096 + e * 64 + d] = f2bf(s);
  }
  if (t < 64) {
    float s = 0.f;
    #pragma unroll
    for (int c = 0; c < 8; ++c) s += kspart[((size_t)bh * 8 + c) * 64 + t];
    ksum[bh * 64 + t] = s;
  }
}

// ---------------- att = (q' @ KV) * z, written in the reference's reshape ---
__global__ __launch_bounds__(256) void att_k(
    const unsigned short* __restrict__ Qp, const unsigned short* __restrict__ KVT,
    const float* __restrict__ ksum, unsigned short* __restrict__ att) {
  __shared__ unsigned short Ql[128 * 64];
  __shared__ unsigned short Kl[64 * 64];
  __shared__ float ksl[64];
  __shared__ float zl[128];
  int bh = blockIdx.y;
  int b = bh >> 4, h = bh & 15;
  int r0 = blockIdx.x * 128;
  int t = threadIdx.x, lane = t & 63, wid = t >> 6;
  int l15 = lane & 15, lhi = lane >> 4;
  #pragma unroll
  for (int i = 0; i < 4; ++i) {
    int cid = i * 256 + t;
    int r = cid >> 3, c8 = cid & 7;
    gload16(Qp + ((size_t)(b * S_LEN + r0 + r)) * D_MODEL + h * DEPTH + c8 * 8,
            &Ql[cid * 8]);
  }
  #pragma unroll
  for (int i = 0; i < 2; ++i) {
    int cid = i * 256 + t;
    gload16(KVT + (size_t)bh * 4096 + cid * 8, &Kl[cid * 8]);
  }
  if (t < 64) ksl[t] = ksum[bh * 64 + t];
  asm volatile("s_waitcnt vmcnt(0)" ::: "memory");
  __syncthreads();
  {
    int r = t >> 1, half = t & 1;
    float s = 0.f;
    #pragma unroll
    for (int j = 0; j < 32; ++j)
      s += bf2f(Ql[r * 64 + half * 32 + j]) * ksl[half * 32 + j];
    s += __shfl_xor(s, 1);
    if (half == 0) zl[r] = 1.f / (s + EPS_K_F);
  }
  __syncthreads();
  f32x4 acc[2][4] = {};
  #pragma unroll
  for (int kk = 0; kk < 2; ++kk) {
    short8 af[2], bfr[4];
    #pragma unroll
    for (int m = 0; m < 2; ++m)
      af[m] = *(const short8*)&Ql[(wid * 32 + m * 16 + l15) * 64 + kk * 32 + lhi * 8];
    #pragma unroll
    for (int n = 0; n < 4; ++n)
      bfr[n] = *(const short8*)&Kl[(n * 16 + l15) * 64 + kk * 32 + lhi * 8];
    #pragma unroll
    for (int m = 0; m < 2; ++m)
      #pragma unroll
      for (int n = 0; n < 4; ++n)
        acc[m][n] = __builtin_amdgcn_mfma_f32_16x16x32_bf16(af[m], bfr[n], acc[m][n], 0, 0, 0);
  }
  #pragma unroll
  for (int m = 0; m < 2; ++m)
    #pragma unroll
    for (int j = 0; j < 4; ++j) {
      int rl = wid * 32 + m * 16 + lhi * 4 + j;
      int n = r0 + rl;
      float z = zl[rl];
      #pragma unroll
      for (int nf = 0; nf < 4; ++nf) {
        int ee = nf * 16 + l15;
        size_t orow = (size_t)b * S_LEN + h * 256 + (n >> 4);
        int ocol = (n & 15) * 64 + ee;
        att[orow * D_MODEL + ocol] = f2bf(acc[m][nf][j] * z);
      }
    }
}

extern "C" void kernel_launch(void* const* d_in, const int* in_sizes, int n_in,
                              void* d_out, int out_size, void* d_ws, size_t ws_size,
                              hipStream_t stream) {
  (void)in_sizes; (void)n_in; (void)out_size; (void)ws_size;
  const float* q     = (const float*)d_in[0];
  const float* k     = (const float*)d_in[1];
  const float* v     = (const float*)d_in[2];
  const float* mask  = (const float*)d_in[3];
  const float* wq    = (const float*)d_in[4];
  const float* wk    = (const float*)d_in[5];
  const float* wv    = (const float*)d_in[6];
  const float* gamma = (const float*)d_in[7];
  const float* beta  = (const float*)d_in[8];
  const float* dw    = (const float*)d_in[9];
  const float* db    = (const float*)d_in[10];
  float* out = (float*)d_out;

  char* ws = (char*)d_ws;
  // buffer plan (lifetimes hand-verified):
  //   ws+0   : Xq (wtrans sidecar) -> gemm_q A -> Qp (ln_act) -> att ->
  //            Cd (dense C) -> ln_final.
  //   ws+32M : Xk (gemm_q sidecar) -> gemm_k A -> dead.
  //   ws+64M : Xv (gemm_k sidecar) -> gemm_v A -> dead.
  //   d_out  : [0,32M) Cq -> Ck -> att-out -> final out;
  //            [32M,64M) Cv -> final out. (Ck/Cv consumed by kv_mfma
  //            before att writes; ln_final overwrites all at the end.)
  unsigned short* Xq  = (unsigned short*)(ws);
  unsigned short* Xk  = (unsigned short*)(ws + 33554432);
  unsigned short* Xv  = (unsigned short*)(ws + 67108864);
  unsigned short* Qp  = Xq;
  unsigned short* Cd  = Xq;
  unsigned short* WqT = (unsigned short*)(ws + 100663296);
  unsigned short* WkT = WqT + 1048576;
  unsigned short* WvT = WkT + 1048576;
  unsigned short* WdT = WvT + 1048576;
  float* part   = (float*)(ws + 109051904);
  float* kspart = (float*)(ws + 117440512);
  unsigned short* KVT = (unsigned short*)(ws + 117964800);
  float* ksum = (float*)(ws + 118489088);
  float* psum  = (float*)(ws + 119537664);  // 1 MB (Q, D reuse)
  float* psq   = (float*)(ws + 120586240);  // 1 MB
  float* psumK = (float*)(ws + 121634816);
  float* psqK  = (float*)(ws + 122683392);
  float* psumV = (float*)(ws + 123731968);
  float* psqV  = (float*)(ws + 124780544);
  float* meanK = (float*)(ws + 125829120);  // 64 KB each
  float* rstdK = (float*)(ws + 125894656);
  float* meanV = (float*)(ws + 125960192);
  float* rstdV = (float*)(ws + 126025728);
  unsigned short* Cq = (unsigned short*)d_out;            // [0,32M)
  unsigned short* Ck = (unsigned short*)d_out;            // [0,32M)
  unsigned short* Cv = (unsigned short*)((char*)d_out + 33554432);
  unsigned short* Catt = (unsigned short*)d_out;          // att out

  dim3 b256(256);
  dim3 b512(512);
  dim3 wtg(32, 32);
  dim3 gemmg(256);
  dim3 lng(ROWS);

  wtrans_k<<<wtg, b256, 0, stream>>>(wq, WqT, q, Xq, 0);
  wtrans_k<<<wtg, b256, 0, stream>>>(wk, WkT, q, Xq, 1);
  wtrans_k<<<wtg, b256, 0, stream>>>(wv, WvT, q, Xq, 2);
  wtrans_k<<<wtg, b256, 0, stream>>>(dw, WdT, q, Xq, 3);

  // gemm_q -> Cq ; sidecar converts k -> Xk ; ln_act -> Qp
  gemm_bt_k<true><<<gemmg, b512, 0, stream>>>(Xq, WqT, Cq, psum, psq, nullptr,
                                              k, Xk, ROWS, D_MODEL, D_MODEL);
  ln_act_k<<<lng, b256, 0, stream>>>(Cq, psum, psq, gamma, beta, Qp);

  // gemm_k -> Ck (raw) ; sidecar converts v -> Xv
  gemm_bt_k<true><<<gemmg, b512, 0, stream>>>(Xk, WkT, Ck, psumK, psqK, nullptr,
                                              v, Xv, ROWS, D_MODEL, D_MODEL);
  // gemm_v -> Cv (raw)
  gemm_bt_k<false><<<gemmg, b512, 0, stream>>>(Xv, WvT, Cv, psumV, psqV, nullptr,
                                               nullptr, nullptr, ROWS, D_MODEL, D_MODEL);

  ln_stats_k<<<dim3(64), b256, 0, stream>>>(psumK, psqK, psumV, psqV,
                                            meanK, rstdK, meanV, rstdV);

  kv_mfma_k<<<dim3(8, 64), b256, 0, stream>>>(Ck, Cv, meanK, rstdK, meanV, rstdV,
                                              mask, gamma, beta, part, kspart);
  kv_reduce_k<<<dim3(64), b256, 0, stream>>>(part, kspart, KVT, ksum);
  att_k<<<dim3(32, 64), b256, 0, stream>>>(Qp, KVT, ksum, Catt);

  gemm_bt_k<false><<<gemmg, b512, 0, stream>>>(Catt, WdT, Cd, psum, psq, db,
                                               nullptr, nullptr, ROWS, D_MODEL, D_MODEL);
  ln_final_k<<<lng, b256, 0, stream>>>(Cd, psum, psq, gamma, beta, out);
}

// Round 17
// 293.108 us; speedup vs baseline: 1.6651x; 1.0609x over previous
//
#include <hip/hip_runtime.h>
#include <hip/hip_bf16.h>
#include <stdint.h>

#define D_MODEL 1024
#define S_LEN   4096
#define BATCH   4
#define HEADS   16
#define DEPTH   64
#define ROWS    (BATCH*S_LEN)   // 16384
#define EPS_K_F 1e-6f
#define EPS_LN_F 1e-6f

typedef __attribute__((ext_vector_type(8))) short short8;
typedef __attribute__((ext_vector_type(4))) float f32x4;

__device__ __forceinline__ unsigned short f2bf(float f) {
  union { float f; unsigned u; } x; x.f = f;
  unsigned r = x.u + 0x7FFF + ((x.u >> 16) & 1);
  return (unsigned short)(r >> 16);
}
__device__ __forceinline__ float bf2f(unsigned short b) {
  union { unsigned u; float f; } x; x.u = ((unsigned)b) << 16;
  return x.f;
}
__device__ __forceinline__ void gload16(const void* g, void* l) {
  __builtin_amdgcn_global_load_lds(
      (const __attribute__((address_space(1))) void*)g,
      (__attribute__((address_space(3))) void*)l, 16, 0, 0);
}

// -------- merged weight transpose x4 + q-conversion sidecar -----------------
// blockIdx.z selects which W to transpose; all 4096 blocks convert q.
__global__ __launch_bounds__(256) void wtrans4_k(
    const float* __restrict__ w0, const float* __restrict__ w1,
    const float* __restrict__ w2, const float* __restrict__ w3,
    unsigned short* __restrict__ t0, unsigned short* __restrict__ t1,
    unsigned short* __restrict__ t2, unsigned short* __restrict__ t3,
    const float* __restrict__ qsrc, unsigned short* __restrict__ qdst) {
  __shared__ float tile[32][33];
  int z = blockIdx.z;
  const float* W = (z == 0) ? w0 : (z == 1) ? w1 : (z == 2) ? w2 : w3;
  unsigned short* Wt = (z == 0) ? t0 : (z == 1) ? t1 : (z == 2) ? t2 : t3;
  int n0 = blockIdx.x * 32, k0 = blockIdx.y * 32;
  int tx = threadIdx.x & 31, ty = threadIdx.x >> 5;
  #pragma unroll
  for (int i = 0; i < 32; i += 8)
    tile[ty + i][tx] = W[(size_t)(k0 + ty + i) * D_MODEL + n0 + tx];
  // q-convert sidecar: block converts 4096 contiguous f32
  {
    int bid = (z * 32 + blockIdx.y) * 32 + blockIdx.x;
    size_t base = (size_t)bid * 4096 + (size_t)threadIdx.x * 8;
    #pragma unroll
    for (int it = 0; it < 2; ++it) {
      size_t off = base + (size_t)it * 2048;
      float4 a = *(const float4*)(qsrc + off);
      float4 b = *(const float4*)(qsrc + off + 4);
      uint4 pk;
      pk.x = (unsigned)f2bf(a.x) | ((unsigned)f2bf(a.y) << 16);
      pk.y = (unsigned)f2bf(a.z) | ((unsigned)f2bf(a.w) << 16);
      pk.z = (unsigned)f2bf(b.x) | ((unsigned)f2bf(b.y) << 16);
      pk.w = (unsigned)f2bf(b.z) | ((unsigned)f2bf(b.w) << 16);
      *(uint4*)(qdst + off) = pk;
    }
  }
  __syncthreads();
  #pragma unroll
  for (int i = 0; i < 32; i += 8)
    Wt[(size_t)(n0 + ty + i) * D_MODEL + k0 + tx] = f2bf(tile[tx][ty + i]);
}

// ===== GEMM: 256x256 tile, 8 waves, BK=64, counted-vmcnt 4-phase pipeline ===
// (identical core to R16; conflict-free swizzle slot = chunk ^ ((row>>1)&3))

#define GEMM_EPILOGUE(HASBIAS)                                               \
  if (HASBIAS) {                                                             \
    float bv[4];                                                             \
    _Pragma("unroll")                                                        \
    for (int n = 0; n < 4; ++n)                                              \
      bv[n] = bias[(int)n0 + wcn * 64 + n * 16 + l15];                       \
    _Pragma("unroll")                                                        \
    for (int m = 0; m < 8; ++m)                                              \
      _Pragma("unroll")                                                      \
      for (int n = 0; n < 4; ++n)                                            \
        _Pragma("unroll")                                                    \
        for (int j = 0; j < 4; ++j)                                          \
          acc[m][n][j] += bv[n];                                             \
  }                                                                          \
  int seg = (int)(n0 >> 6) + wcn;                                            \
  _Pragma("unroll")                                                          \
  for (int m = 0; m < 8; ++m) {                                              \
    float s[4], s2[4];                                                       \
    _Pragma("unroll")                                                        \
    for (int j = 0; j < 4; ++j) {                                            \
      float a = 0.f, b = 0.f;                                                \
      _Pragma("unroll")                                                      \
      for (int n = 0; n < 4; ++n) { float x = acc[m][n][j]; a += x; b += x*x; } \
      s[j] = a; s2[j] = b;                                                   \
    }                                                                        \
    _Pragma("unroll")                                                        \
    for (int off = 1; off < 16; off <<= 1) {                                 \
      _Pragma("unroll")                                                      \
      for (int j = 0; j < 4; ++j) {                                          \
        s[j]  += __shfl_xor(s[j],  off);                                     \
        s2[j] += __shfl_xor(s2[j], off);                                     \
      }                                                                      \
    }                                                                        \
    if (l15 == 0) {                                                          \
      _Pragma("unroll")                                                      \
      for (int j = 0; j < 4; ++j) {                                          \
        int rg = (int)m0 + wr * 128 + m * 16 + lhi * 4 + j;                  \
        psum[rg * 16 + seg] = s[j];                                          \
        psq [rg * 16 + seg] = s2[j];                                         \
      }                                                                      \
    }                                                                        \
  }                                                                          \
  _Pragma("unroll")                                                          \
  for (int m = 0; m < 8; ++m)                                                \
    _Pragma("unroll")                                                        \
    for (int j = 0; j < 4; ++j) {                                            \
      size_t row = m0 + wr * 128 + m * 16 + lhi * 4 + j;                     \
      _Pragma("unroll")                                                      \
      for (int n = 0; n < 4; ++n) {                                          \
        int col = (int)n0 + wcn * 64 + n * 16 + l15;                         \
        Cb[row * N + col] = f2bf(acc[m][n][j]);                              \
      }                                                                      \
    }

#define STAGE_HALF(kof_, slot_, h_) do {                                     \
    _Pragma("unroll")                                                        \
    for (int j = 0; j < 2; ++j) {                                            \
      int idx = j * 512 + t; int r_ = idx >> 2; int cs_ = idx & 3;           \
      int c_ = cs_ ^ ((r_ >> 1) & 3);                                        \
      gload16(A + (m0 + r_) * (size_t)K + (kof_) + (h_) * 32 + c_ * 8,       \
              &Al[slot_][(h_) * 8192 + idx * 8]);                            \
    }                                                                        \
    _Pragma("unroll")                                                        \
    for (int j = 0; j < 2; ++j) {                                            \
      int idx = j * 512 + t; int r_ = idx >> 2; int cs_ = idx & 3;           \
      int c_ = cs_ ^ ((r_ >> 1) & 3);                                        \
      gload16(Bt + (n0 + r_) * (size_t)K + (kof_) + (h_) * 32 + c_ * 8,      \
              &Bl[slot_][(h_) * 8192 + idx * 8]);                            \
    }                                                                        \
  } while (0)

#define PH_READ_B(kk_)                                                       \
    _Pragma("unroll")                                                        \
    for (int n = 0; n < 4; ++n) {                                            \
      int rb_ = wcn * 64 + n * 16 + l15;                                     \
      bfr[n] = *(const short8*)&Bl[slot][(kk_) * 8192 + rb_ * 32 + cswz];    \
    }
#define PH_READ_A(kk_, mh_)                                                  \
    _Pragma("unroll")                                                        \
    for (int m = 0; m < 4; ++m) {                                            \
      int ra_ = wr * 128 + ((mh_) * 4 + m) * 16 + l15;                       \
      af[m] = *(const short8*)&Al[slot][(kk_) * 8192 + ra_ * 32 + cswz];     \
    }
#define PH_MFMA(mh_)                                                         \
    __builtin_amdgcn_s_setprio(1);                                           \
    _Pragma("unroll")                                                        \
    for (int m = 0; m < 4; ++m)                                              \
      _Pragma("unroll")                                                      \
      for (int n = 0; n < 4; ++n)                                            \
        acc[(mh_) * 4 + m][n] = __builtin_amdgcn_mfma_f32_16x16x32_bf16(     \
            af[m], bfr[n], acc[(mh_) * 4 + m][n], 0, 0, 0);                  \
    __builtin_amdgcn_s_setprio(0);
#define LGKM0                                                                \
    asm volatile("s_waitcnt lgkmcnt(0)" ::: "memory");                       \
    __builtin_amdgcn_sched_barrier(0);

#define SIDE_PACK_STORE(chunk_) do {                                         \
    uint4 pk_;                                                               \
    pk_.x = (unsigned)f2bf(sreg0.x) | ((unsigned)f2bf(sreg0.y) << 16);       \
    pk_.y = (unsigned)f2bf(sreg0.z) | ((unsigned)f2bf(sreg0.w) << 16);       \
    pk_.z = (unsigned)f2bf(sreg1.x) | ((unsigned)f2bf(sreg1.y) << 16);       \
    pk_.w = (unsigned)f2bf(sreg1.z) | ((unsigned)f2bf(sreg1.w) << 16);       \
    *(uint4*)(side_dst + sbase + (size_t)(chunk_) * 4096) = pk_;             \
  } while (0)
#define SIDE_LOAD(chunk_) do {                                               \
    const float* sp_ = side_src + sbase + (size_t)(chunk_) * 4096;           \
    sreg0 = *(const float4*)sp_; sreg1 = *(const float4*)(sp_ + 4);          \
  } while (0)

#define TAIL_TILE(slot_) do {                                                \
    const int slot = (slot_);                                                \
    short8 af[4], bfr[4];                                                    \
    PH_READ_B(0) PH_READ_A(0, 0) LGKM0 PH_MFMA(0)                            \
    PH_READ_A(0, 1) LGKM0 PH_MFMA(1)                                         \
    PH_READ_B(1) PH_READ_A(1, 0) LGKM0 PH_MFMA(0)                            \
    PH_READ_A(1, 1) LGKM0 PH_MFMA(1)                                         \
  } while (0)

template <bool SIDECAR>
__global__ __launch_bounds__(512) void gemm_bt_k(
    const unsigned short* __restrict__ A,
    const unsigned short* __restrict__ Bt,
    unsigned short* __restrict__ Cb,
    float* __restrict__ psum, float* __restrict__ psq,
    const float* __restrict__ bias,
    const float* __restrict__ side_src,
    unsigned short* __restrict__ side_dst,
    int M, int N, int K) {
  __shared__ unsigned short Al[2][16384];
  __shared__ unsigned short Bl[2][16384];
  int t = threadIdx.x;
  int lane = t & 63, wid = t >> 6;
  int wr = wid >> 2, wcn = wid & 3;
  int l15 = lane & 15, lhi = lane >> 4;
  const int cswz = (lhi ^ ((l15 >> 1) & 3)) << 3;
  int p = blockIdx.x;
  int cb = (p >> 3) & 3;
  int rb = (p & 7) | ((p >> 5) << 3);
  size_t m0 = (size_t)rb * 256, n0 = (size_t)cb * 256;
  f32x4 acc[8][4] = {};

  const int KT = K >> 6;

  float4 sreg0 = {}, sreg1 = {};
  size_t sbase = (size_t)p * 65536 + (size_t)t * 8;

  if (SIDECAR) SIDE_LOAD(0);
  STAGE_HALF(0, 0, 0);  STAGE_HALF(0, 0, 1);
  STAGE_HALF(64, 1, 0); STAGE_HALF(64, 1, 1);
  asm volatile("s_waitcnt vmcnt(8)" ::: "memory");
  __builtin_amdgcn_s_barrier();
  __builtin_amdgcn_sched_barrier(0);

  for (int kt = 0; kt < KT - 2; ++kt) {
    const int slot = kt & 1;
    short8 af[4], bfr[4];
    PH_READ_B(0)
    PH_READ_A(0, 0)
    LGKM0
    PH_MFMA(0)
    PH_READ_A(0, 1)
    LGKM0
    __builtin_amdgcn_s_barrier();
    __builtin_amdgcn_sched_barrier(0);
    STAGE_HALF((kt + 2) << 6, slot, 0);
    __builtin_amdgcn_sched_barrier(0);
    PH_MFMA(1)
    PH_READ_B(1)
    PH_READ_A(1, 0)
    LGKM0
    PH_MFMA(0)
    PH_READ_A(1, 1)
    LGKM0
    __builtin_amdgcn_s_barrier();
    __builtin_amdgcn_sched_barrier(0);
    STAGE_HALF((kt + 2) << 6, slot, 1);
    __builtin_amdgcn_sched_barrier(0);
    PH_MFMA(1)
    if (SIDECAR) {
      SIDE_PACK_STORE(kt);
      SIDE_LOAD(kt + 1);
      __builtin_amdgcn_sched_barrier(0);
      asm volatile("s_waitcnt vmcnt(11)" ::: "memory");
    } else {
      asm volatile("s_waitcnt vmcnt(8)" ::: "memory");
    }
    __builtin_amdgcn_s_barrier();
    __builtin_amdgcn_sched_barrier(0);
  }

  TAIL_TILE((KT - 2) & 1);
  if (SIDECAR) {
    SIDE_PACK_STORE(KT - 2);
    SIDE_LOAD(KT - 1);
    __builtin_amdgcn_sched_barrier(0);
    asm volatile("s_waitcnt vmcnt(3)" ::: "memory");
  } else {
    asm volatile("s_waitcnt vmcnt(0)" ::: "memory");
  }
  __builtin_amdgcn_s_barrier();
  __builtin_amdgcn_sched_barrier(0);

  TAIL_TILE((KT - 1) & 1);
  if (SIDECAR) SIDE_PACK_STORE(KT - 1);

  GEMM_EPILOGUE(bias != nullptr)
}

// ---------------- LN stats: per-row mean/rstd from partials (Q, K, V) -------
__global__ __launch_bounds__(256) void ln_stats_k(
    const float* __restrict__ psumQ, const float* __restrict__ psqQ,
    const float* __restrict__ psumK, const float* __restrict__ psqK,
    const float* __restrict__ psumV, const float* __restrict__ psqV,
    float* __restrict__ meanQ, float* __restrict__ rstdQ,
    float* __restrict__ meanK, float* __restrict__ rstdK,
    float* __restrict__ meanV, float* __restrict__ rstdV) {
  int row = blockIdx.x * 256 + threadIdx.x;
  float sQ = 0.f, s2Q = 0.f, sK = 0.f, s2K = 0.f, sV = 0.f, s2V = 0.f;
  #pragma unroll
  for (int i = 0; i < 16; ++i) {
    sQ += psumQ[row * 16 + i]; s2Q += psqQ[row * 16 + i];
    sK += psumK[row * 16 + i]; s2K += psqK[row * 16 + i];
    sV += psumV[row * 16 + i]; s2V += psqV[row * 16 + i];
  }
  float mQ = sQ * (1.f / D_MODEL);
  float mK = sK * (1.f / D_MODEL);
  float mV = sV * (1.f / D_MODEL);
  meanQ[row] = mQ;
  rstdQ[row] = rsqrtf(s2Q * (1.f / D_MODEL) - mQ * mQ + EPS_LN_F);
  meanK[row] = mK;
  rstdK[row] = rsqrtf(s2K * (1.f / D_MODEL) - mK * mK + EPS_LN_F);
  meanV[row] = mV;
  rstdV[row] = rsqrtf(s2V * (1.f / D_MODEL) - mV * mV + EPS_LN_F);
}

// ---------------- final LayerNorm from bf16 C + partials -> f32 out ---------
__global__ __launch_bounds__(256) void ln_final_k(
    const unsigned short* __restrict__ Cb,
    const float* __restrict__ psum, const float* __restrict__ psq,
    const float* __restrict__ gamma, const float* __restrict__ beta,
    float* __restrict__ out) {
  int row = blockIdx.x;
  int t = threadIdx.x;
  float s = 0.f, s2 = 0.f;
  #pragma unroll
  for (int i = 0; i < 16; ++i) { s += psum[row * 16 + i]; s2 += psq[row * 16 + i]; }
  float mean = s * (1.f / D_MODEL);
  float var = s2 * (1.f / D_MODEL) - mean * mean;
  float rstd = rsqrtf(var + EPS_LN_F);
  ushort4 cv = ((const ushort4*)(Cb + (size_t)row * D_MODEL))[t];
  float4 gv = ((const float4*)gamma)[t];
  float4 bv = ((const float4*)beta)[t];
  float4 w;
  w.x = (bf2f(cv.x) - mean) * rstd * gv.x + bv.x;
  w.y = (bf2f(cv.y) - mean) * rstd * gv.y + bv.y;
  w.z = (bf2f(cv.z) - mean) * rstd * gv.z + bv.z;
  w.w = (bf2f(cv.w) - mean) * rstd * gv.w + bv.w;
  ((float4*)(out + (size_t)row * D_MODEL))[t] = w;
}

// ---------------- KV via MFMA, with fused LN+activation on staging ----------
__global__ __launch_bounds__(256) void kv_mfma_k(
    const unsigned short* __restrict__ Ck, const unsigned short* __restrict__ Cv,
    const float* __restrict__ meanK, const float* __restrict__ rstdK,
    const float* __restrict__ meanV, const float* __restrict__ rstdV,
    const float* __restrict__ mask,
    const float* __restrict__ gamma, const float* __restrict__ beta,
    float* __restrict__ part, float* __restrict__ kspart) {
  __shared__ unsigned short Kl[4096];
  __shared__ unsigned short Vl[4096];
  int bh = blockIdx.y, chunk = blockIdx.x;
  int b_ = bh >> 4, h = bh & 15;
  int t = threadIdx.x, lane = t & 63, w = t >> 6;
  int l15 = lane & 15, g = lane >> 4;

  int sn = t >> 2, sd16 = t & 3;
  int sc = sd16 ^ ((sn >> 3) & 3);
  size_t goff = (size_t)sn * D_MODEL + h * DEPTH + sd16 * 16;
  int ldst = sn * 64 + sc * 16;

  float g16[16], b16[16];
  {
    int cbase = h * DEPTH + sd16 * 16;
    #pragma unroll
    for (int i = 0; i < 4; ++i) {
      float4 gv = *(const float4*)(gamma + cbase + i * 4);
      float4 bv = *(const float4*)(beta + cbase + i * 4);
      g16[i*4+0] = gv.x; g16[i*4+1] = gv.y; g16[i*4+2] = gv.z; g16[i*4+3] = gv.w;
      b16[i*4+0] = bv.x; b16[i*4+1] = bv.y; b16[i*4+2] = bv.z; b16[i*4+3] = bv.w;
    }
  }

  short8 ones;
  #pragma unroll
  for (int i = 0; i < 8; ++i) ones[i] = (short)0x3F80;

  f32x4 acc[4] = {};
  f32x4 ks = {};

  int baseA = ((w ^ g) << 4) + l15;
  int baseB0 = ((0 ^ g) << 4) + l15;
  int baseB1 = ((1 ^ g) << 4) + l15;
  int baseB2 = ((2 ^ g) << 4) + l15;
  int baseB3 = ((3 ^ g) << 4) + l15;

  int rowbase_r = b_ * S_LEN + chunk * 512;
  size_t rowbase = (size_t)rowbase_r * D_MODEL;
  for (int tile = 0; tile < 8; ++tile) {
    const unsigned short* kg = Ck + rowbase + (size_t)tile * 64 * D_MODEL + goff;
    const unsigned short* vg = Cv + rowbase + (size_t)tile * 64 * D_MODEL + goff;
    uint4 ra = *(const uint4*)kg;
    uint4 rb = *(const uint4*)(kg + 8);
    uint4 rc = *(const uint4*)vg;
    uint4 rd = *(const uint4*)(vg + 8);
    int grow = rowbase_r + tile * 64 + sn;
    float mk  = mask[grow];
    float mKv = meanK[grow], rKv = rstdK[grow];
    float mVv = meanV[grow], rVv = rstdV[grow];
    union { uint4 u[2]; unsigned short s[16]; } kin, vin, kout, vout;
    kin.u[0] = ra; kin.u[1] = rb;
    vin.u[0] = rc; vin.u[1] = rd;
    #pragma unroll
    for (int j = 0; j < 16; ++j) {
      float lnk = (bf2f(kin.s[j]) - mKv) * rKv * g16[j] + b16[j];
      kout.s[j] = f2bf((fmaxf(lnk, 0.f) + EPS_K_F) * mk);
      float lnv = (bf2f(vin.s[j]) - mVv) * rVv * g16[j] + b16[j];
      vout.s[j] = f2bf(lnv * mk);
    }
    __syncthreads();
    *(uint4*)&Kl[ldst]     = kout.u[0];
    *(uint4*)&Kl[ldst + 8] = kout.u[1];
    *(uint4*)&Vl[ldst]     = vout.u[0];
    *(uint4*)&Vl[ldst + 8] = vout.u[1];
    __syncthreads();
    #pragma unroll
    for (int kk = 0; kk < 2; ++kk) {
      int nb = (kk * 32 + g * 8) * 64;
      short8 af, bf0, bf1, bf2, bf3;
      #pragma unroll
      for (int i = 0; i < 8; ++i) {
        int rowoff = nb + i * 64;
        af[i]  = (short)Kl[rowoff + baseA];
        bf0[i] = (short)Vl[rowoff + baseB0];
        bf1[i] = (short)Vl[rowoff + baseB1];
        bf2[i] = (short)Vl[rowoff + baseB2];
        bf3[i] = (short)Vl[rowoff + baseB3];
      }
      acc[0] = __builtin_amdgcn_mfma_f32_16x16x32_bf16(af, bf0, acc[0], 0, 0, 0);
      acc[1] = __builtin_amdgcn_mfma_f32_16x16x32_bf16(af, bf1, acc[1], 0, 0, 0);
      acc[2] = __builtin_amdgcn_mfma_f32_16x16x32_bf16(af, bf2, acc[2], 0, 0, 0);
      acc[3] = __builtin_amdgcn_mfma_f32_16x16x32_bf16(af, bf3, acc[3], 0, 0, 0);
      ks     = __builtin_amdgcn_mfma_f32_16x16x32_bf16(af, ones, ks, 0, 0, 0);
    }
  }
  float* pp = part + ((size_t)bh * 8 + chunk) * 4096;
  #pragma unroll
  for (int nf = 0; nf < 4; ++nf)
    #pragma unroll
    for (int r = 0; r < 4; ++r)
      pp[(16 * w + 4 * g + r) * 64 + 16 * nf + l15] = acc[nf][r];
  if (l15 == 0) {
    #pragma unroll
    for (int r = 0; r < 4; ++r)
      kspart[((size_t)bh * 8 + chunk) * 64 + 16 * w + 4 * g + r] = ks[r];
  }
}

// ---------------- KV reduce -> KV^T bf16 ([e][d]) + ksum f32 ----------------
__global__ __launch_bounds__(256) void kv_reduce_k(
    const float* __restrict__ part, const float* __restrict__ kspart,
    unsigned short* __restrict__ KVT, float* __restrict__ ksum) {
  int bh = blockIdx.x, t = threadIdx.x;
  for (int idx = t; idx < 4096; idx += 256) {
    int d = idx >> 6, e = idx & 63;
    float s = 0.f;
    #pragma unroll
    for (int c = 0; c < 8; ++c)
      s += part[((size_t)bh * 8 + c) * 4096 + d * 64 + e];
    KVT[(size_t)bh * 4096 + e * 64 + d] = f2bf(s);
  }
  if (t < 64) {
    float s = 0.f;
    #pragma unroll
    for (int c = 0; c < 8; ++c) s += kspart[((size_t)bh * 8 + c) * 64 + t];
    ksum[bh * 64 + t] = s;
  }
}

// ---------------- att = (q' @ KV) * z, with fused Q-LN on staging -----------
// Reads RAW Cq; applies q' = relu(ln)+eps between register load and
// swizzled LDS write. Ql layout: elem (r,c) at r*64 + ((c>>3 ^ (r&7))<<3)
// + (c&7)  (conflict-free: frag rows rr have rr&7 = l15&7 -> all 8 bank
// groups uniform; staging waves likewise).
__global__ __launch_bounds__(256) void att_k(
    const unsigned short* __restrict__ Cq,
    const float* __restrict__ meanQ, const float* __restrict__ rstdQ,
    const float* __restrict__ gamma, const float* __restrict__ beta,
    const unsigned short* __restrict__ KVT,
    const float* __restrict__ ksum, unsigned short* __restrict__ att) {
  __shared__ unsigned short Ql[128 * 64];
  __shared__ unsigned short Kl[64 * 64];
  __shared__ float ksl[64];
  __shared__ float zl[128];
  int bh = blockIdx.y;
  int b = bh >> 4, h = bh & 15;
  int r0 = blockIdx.x * 128;
  int t = threadIdx.x, lane = t & 63, wid = t >> 6;
  int l15 = lane & 15, lhi = lane >> 4;

  // KVT + ksum staging (linear, gload16)
  #pragma unroll
  for (int i = 0; i < 2; ++i) {
    int cid = i * 256 + t;
    gload16(KVT + (size_t)bh * 4096 + cid * 8, &Kl[cid * 8]);
  }
  if (t < 64) ksl[t] = ksum[bh * 64 + t];

  // Q staging with fused LN: thread t owns row r = t&127, col-half = t>>7
  {
    int r = t & 127, half = t >> 7;
    int grow = b * S_LEN + r0 + r;
    float mean = meanQ[grow], rstd = rstdQ[grow];
    int cbase = h * DEPTH + half * 32;
    float g32[32], b32[32];
    #pragma unroll
    for (int i = 0; i < 8; ++i) {
      float4 gv = *(const float4*)(gamma + cbase + i * 4);
      float4 bv = *(const float4*)(beta + cbase + i * 4);
      g32[i*4+0] = gv.x; g32[i*4+1] = gv.y; g32[i*4+2] = gv.z; g32[i*4+3] = gv.w;
      b32[i*4+0] = bv.x; b32[i*4+1] = bv.y; b32[i*4+2] = bv.z; b32[i*4+3] = bv.w;
    }
    const unsigned short* src = Cq + (size_t)grow * D_MODEL + cbase;
    #pragma unroll
    for (int i = 0; i < 4; ++i) {
      union { uint4 u; unsigned short s[8]; } in, outp;
      in.u = *(const uint4*)(src + i * 8);
      #pragma unroll
      for (int j = 0; j < 8; ++j) {
        float ln = (bf2f(in.s[j]) - mean) * rstd * g32[i*8+j] + b32[i*8+j];
        outp.s[j] = f2bf(fmaxf(ln, 0.f) + EPS_K_F);
      }
      int cg = half * 4 + i;                      // global chunk 0..7
      *(uint4*)&Ql[r * 64 + ((cg ^ (r & 7)) << 3)] = outp.u;
    }
  }
  asm volatile("s_waitcnt vmcnt(0)" ::: "memory");
  __syncthreads();
  {
    int r = t >> 1, half = t & 1;
    float s = 0.f;
    #pragma unroll
    for (int j = 0; j < 32; ++j) {
      int col = half * 32 + j;
      s += bf2f(Ql[r * 64 + (((col >> 3) ^ (r & 7)) << 3) + (col & 7)]) *
           ksl[col];
    }
    s += __shfl_xor(s, 1);
    if (half == 0) zl[r] = 1.f / (s + EPS_K_F);
  }
  __syncthreads();
  f32x4 acc[2][4] = {};
  #pragma unroll
  for (int kk = 0; kk < 2; ++kk) {
    short8 af[2], bfr[4];
    #pragma unroll
    for (int m = 0; m < 2; ++m) {
      int rr = wid * 32 + m * 16 + l15;
      int cx = kk * 4 + lhi;
      af[m] = *(const short8*)&Ql[rr * 64 + ((cx ^ (rr & 7)) << 3)];
    }
    #pragma unroll
    for (int n = 0; n < 4; ++n)
      bfr[n] = *(const short8*)&Kl[(n * 16 + l15) * 64 + kk * 32 + lhi * 8];
    #pragma unroll
    for (int m = 0; m < 2; ++m)
      #pragma unroll
      for (int n = 0; n < 4; ++n)
        acc[m][n] = __builtin_amdgcn_mfma_f32_16x16x32_bf16(af[m], bfr[n], acc[m][n], 0, 0, 0);
  }
  #pragma unroll
  for (int m = 0; m < 2; ++m)
    #pragma unroll
    for (int j = 0; j < 4; ++j) {
      int rl = wid * 32 + m * 16 + lhi * 4 + j;
      int n = r0 + rl;
      float z = zl[rl];
      #pragma unroll
      for (int nf = 0; nf < 4; ++nf) {
        int ee = nf * 16 + l15;
        size_t orow = (size_t)b * S_LEN + h * 256 + (n >> 4);
        int ocol = (n & 15) * 64 + ee;
        att[orow * D_MODEL + ocol] = f2bf(acc[m][nf][j] * z);
      }
    }
}

extern "C" void kernel_launch(void* const* d_in, const int* in_sizes, int n_in,
                              void* d_out, int out_size, void* d_ws, size_t ws_size,
                              hipStream_t stream) {
  (void)in_sizes; (void)n_in; (void)out_size; (void)ws_size;
  const float* q     = (const float*)d_in[0];
  const float* k     = (const float*)d_in[1];
  const float* v     = (const float*)d_in[2];
  const float* mask  = (const float*)d_in[3];
  const float* wq    = (const float*)d_in[4];
  const float* wk    = (const float*)d_in[5];
  const float* wv    = (const float*)d_in[6];
  const float* gamma = (const float*)d_in[7];
  const float* beta  = (const float*)d_in[8];
  const float* dw    = (const float*)d_in[9];
  const float* db    = (const float*)d_in[10];
  float* out = (float*)d_out;

  char* ws = (char*)d_ws;
  // buffer plan (lifetimes hand-verified):
  //   ws+0   : Xq (wtrans4 sidecar) -> gemm_q A -> dead -> Ck (gemm_k out)
  //            -> kv_mfma -> dead -> Cd (gemm_d out) -> ln_final.
  //   ws+32M : Xk (gemm_q sidecar) -> gemm_k A -> dead -> Catt (att out)
  //            -> gemm_d A.
  //   ws+64M : Xv (gemm_k sidecar) -> gemm_v A -> dead.
  //   d_out  : [0,32M) Cq (gemm_q out) -> att (fused Q-LN) reads;
  //            [32M,64M) Cv (gemm_v out) -> kv_mfma. ln_final overwrites
  //            all of d_out at the end (after all readers done).
  unsigned short* Xq  = (unsigned short*)(ws);
  unsigned short* Ck  = (unsigned short*)(ws);
  unsigned short* Cd  = (unsigned short*)(ws);
  unsigned short* Xk  = (unsigned short*)(ws + 33554432);
  unsigned short* Catt= (unsigned short*)(ws + 33554432);
  unsigned short* Xv  = (unsigned short*)(ws + 67108864);
  unsigned short* WqT = (unsigned short*)(ws + 100663296);
  unsigned short* WkT = WqT + 1048576;
  unsigned short* WvT = WkT + 1048576;
  unsigned short* WdT = WvT + 1048576;
  float* part   = (float*)(ws + 109051904);
  float* kspart = (float*)(ws + 117440512);
  unsigned short* KVT = (unsigned short*)(ws + 117964800);
  float* ksum  = (float*)(ws + 118489088);
  float* psum  = (float*)(ws + 119537664);  // 1 MB (D)
  float* psq   = (float*)(ws + 120586240);  // 1 MB
  float* psumK = (float*)(ws + 121634816);
  float* psqK  = (float*)(ws + 122683392);
  float* psumV = (float*)(ws + 123731968);
  float* psqV  = (float*)(ws + 124780544);
  float* psumQ = (float*)(ws + 125829120);
  float* psqQ  = (float*)(ws + 126877696);
  float* meanK = (float*)(ws + 127926272);  // 64 KB each
  float* rstdK = (float*)(ws + 127991808);
  float* meanV = (float*)(ws + 128057344);
  float* rstdV = (float*)(ws + 128122880);
  float* meanQ = (float*)(ws + 128188416);
  float* rstdQ = (float*)(ws + 128253952);
  unsigned short* Cq = (unsigned short*)d_out;            // [0,32M)
  unsigned short* Cv = (unsigned short*)((char*)d_out + 33554432);

  dim3 b256(256);
  dim3 b512(512);
  dim3 wtg(32, 32, 4);
  dim3 gemmg(256);
  dim3 lng(ROWS);

  wtrans4_k<<<wtg, b256, 0, stream>>>(wq, wk, wv, dw, WqT, WkT, WvT, WdT, q, Xq);

  // gemm_q -> Cq (raw, d_out) ; sidecar converts k -> Xk
  gemm_bt_k<true><<<gemmg, b512, 0, stream>>>(Xq, WqT, Cq, psumQ, psqQ, nullptr,
                                              k, Xk, ROWS, D_MODEL, D_MODEL);
  // gemm_k -> Ck (raw, ws+0) ; sidecar converts v -> Xv
  gemm_bt_k<true><<<gemmg, b512, 0, stream>>>(Xk, WkT, Ck, psumK, psqK, nullptr,
                                              v, Xv, ROWS, D_MODEL, D_MODEL);
  // gemm_v -> Cv (raw, d_out+32M)
  gemm_bt_k<false><<<gemmg, b512, 0, stream>>>(Xv, WvT, Cv, psumV, psqV, nullptr,
                                               nullptr, nullptr, ROWS, D_MODEL, D_MODEL);

  ln_stats_k<<<dim3(64), b256, 0, stream>>>(psumQ, psqQ, psumK, psqK, psumV, psqV,
                                            meanQ, rstdQ, meanK, rstdK, meanV, rstdV);

  kv_mfma_k<<<dim3(8, 64), b256, 0, stream>>>(Ck, Cv, meanK, rstdK, meanV, rstdV,
                                              mask, gamma, beta, part, kspart);
  kv_reduce_k<<<dim3(64), b256, 0, stream>>>(part, kspart, KVT, ksum);
  att_k<<<dim3(32, 64), b256, 0, stream>>>(Cq, meanQ, rstdQ, gamma, beta,
                                           KVT, ksum, Catt);

  gemm_bt_k<false><<<gemmg, b512, 0, stream>>>(Catt, WdT, Cd, psum, psq, db,
                                               nullptr, nullptr, ROWS, D_MODEL, D_MODEL);
  ln_final_k<<<lng, b256, 0, stream>>>(Cd, psum, psq, gamma, beta, out);
}